// Round 5
// baseline (174.469 us; speedup 1.0000x reference)
//
#include <hip/hip_runtime.h>
#include <math.h>

#define TDIM 1026
#define KP 1056          // K padded for LV GEMM (33 * 32)
#define NP 1152          // N padded for LV GEMM (9 * 128)
#define KSPLIT 7

typedef __attribute__((ext_vector_type(8))) short bf16x8;
typedef __attribute__((ext_vector_type(4))) float f32x4;

// ---- fp32 -> bf16 RNE helpers ------------------------------------------------
__device__ inline unsigned int pk_bf16(float a, float b) {
    unsigned int ua = __float_as_uint(a), ub = __float_as_uint(b);
    ua = (ua + 0x7FFFu + ((ua >> 16) & 1u)) >> 16;
    ub = (ub + 0x7FFFu + ((ub >> 16) & 1u)) & 0xFFFF0000u;
    return ua | ub;
}
__device__ inline unsigned short f2bf(float a) {
    unsigned int ua = __float_as_uint(a);
    return (unsigned short)((ua + 0x7FFFu + ((ua >> 16) & 1u)) >> 16);
}

// ---- convert + transpose both weight matrices to bf16 [n][k] -----------------
// z=0: W_lv (1026x1026) -> Wlt [n][KP] zero-padded; z=1: W_fe (512x512) -> Wt [n][512].
__global__ __launch_bounds__(256)
void k_cvtboth(const float* __restrict__ Wfe, const float* __restrict__ Wlv,
               unsigned short* __restrict__ Wt, unsigned short* __restrict__ Wlt)
{
    __shared__ float T[32][33];
    const int z = blockIdx.z;
    if (z && (blockIdx.x >= 16 || blockIdx.y >= 16)) return;
    const float* W = z ? Wfe : Wlv;
    unsigned short* D = z ? Wt : Wlt;
    const int S  = z ? 512 : TDIM;
    const int DS = z ? 512 : KP;
    const int n0 = blockIdx.x * 32, k0 = blockIdx.y * 32;
    const int t = threadIdx.x;
    {
        int ky = t >> 3, nx = (t & 7) * 4;
#pragma unroll
        for (int i = 0; i < 4; ++i) {
            float v = 0.f;
            if (k0 + ky < S && n0 + nx + i < S)
                v = W[(size_t)(k0 + ky) * S + n0 + nx + i];
            T[nx + i][ky] = v;
        }
    }
    __syncthreads();
    {
        int ny = t >> 3, kx = (t & 7) * 4;
        ushort4 o;
        o.x = f2bf(T[ny][kx + 0]); o.y = f2bf(T[ny][kx + 1]);
        o.z = f2bf(T[ny][kx + 2]); o.w = f2bf(T[ny][kx + 3]);
        *(ushort4*)(D + (size_t)(n0 + ny) * DS + k0 + kx) = o;
    }
}

// ---- Kernel 1 (fast): bf16 MFMA FE GEMM, fused fp32->bf16 convert of A,
// register-prefetch pipelined; + bias/relu + per-episode stats epilogue --------
__global__ __launch_bounds__(256)
void k_fe_mfma(const float* __restrict__ Atr, const float* __restrict__ Ate,
               const unsigned short* __restrict__ Wt,
               const float* __restrict__ bfe, float* __restrict__ Z,
               unsigned short* __restrict__ Zb, float* __restrict__ muT_te)
{
    __shared__ unsigned short As[128 * 40];
    __shared__ unsigned short Bs[128 * 40];
    __shared__ float2 sbuf[4 * 128];

    const int tid  = threadIdx.x;
    const int lane = tid & 63;
    const int wave = tid >> 6;
    const int wr = wave >> 1, wc = wave & 1;
    const int m = lane & 15, quad = lane >> 4;
    const int col0 = blockIdx.x * 128;
    const int row0 = blockIdx.y * 128;
    const float* A = (row0 < 8192) ? Atr : Ate;
    const int ar0 = row0 & 8191;

    f32x4 acc[4][4];
#pragma unroll
    for (int i = 0; i < 4; ++i)
#pragma unroll
        for (int j = 0; j < 4; ++j) acc[i][j] = (f32x4){0.f, 0.f, 0.f, 0.f};

    const int srow = tid >> 2;   // rows srow, srow+64
    const int skc  = tid & 3;    // k sub-offset (8 elems)

    float4 pa0[2], pa1[2];       // prefetched A (fp32)
    uint4  pb[2];                // prefetched B (bf16)

#define FE_PRELOAD(K0)                                                              \
    {                                                                               \
        _Pragma("unroll")                                                           \
        for (int s = 0; s < 2; ++s) {                                               \
            int row = srow + s * 64;                                                \
            const float* ap = A + (size_t)(ar0 + row) * 512 + (K0) + skc * 8;       \
            pa0[s] = *(const float4*)(ap);                                          \
            pa1[s] = *(const float4*)(ap + 4);                                      \
            pb[s]  = *(const uint4*)(Wt + (size_t)(col0 + row) * 512 + (K0) + skc * 8); \
        }                                                                           \
    }

    FE_PRELOAD(0)
    for (int k0 = 0; k0 < 512; k0 += 32) {
        __syncthreads();
#pragma unroll
        for (int s = 0; s < 2; ++s) {
            int row = srow + s * 64;
            uint4 va;
            va.x = pk_bf16(pa0[s].x, pa0[s].y); va.y = pk_bf16(pa0[s].z, pa0[s].w);
            va.z = pk_bf16(pa1[s].x, pa1[s].y); va.w = pk_bf16(pa1[s].z, pa1[s].w);
            *(uint4*)(As + row * 40 + skc * 8) = va;
            *(uint4*)(Bs + row * 40 + skc * 8) = pb[s];
        }
        __syncthreads();
        if (k0 + 32 < 512) FE_PRELOAD(k0 + 32)   // overlaps ds_read+MFMA below
        bf16x8 af[4], bfr[4];
#pragma unroll
        for (int t2 = 0; t2 < 4; ++t2) {
            af[t2]  = *(const bf16x8*)(As + (wr * 64 + t2 * 16 + m) * 40 + quad * 8);
            bfr[t2] = *(const bf16x8*)(Bs + (wc * 64 + t2 * 16 + m) * 40 + quad * 8);
        }
#pragma unroll
        for (int ti = 0; ti < 4; ++ti)
#pragma unroll
            for (int tj = 0; tj < 4; ++tj)
                acc[ti][tj] = __builtin_amdgcn_mfma_f32_16x16x32_bf16(
                    af[ti], bfr[tj], acc[ti][tj], 0, 0, 0);
    }

    // epilogue: bias + relu, per-episode (32-row) column sums of v, v^2
#pragma unroll
    for (int ep = 0; ep < 2; ++ep) {
#pragma unroll
        for (int tj = 0; tj < 4; ++tj) {
            int colL = wc * 64 + tj * 16 + m;
            float b = bfe[col0 + colL];
            float s1 = 0.f, s2 = 0.f;
#pragma unroll
            for (int p = 0; p < 2; ++p) {
                int ti = ep * 2 + p;
#pragma unroll
                for (int r = 0; r < 4; ++r) {
                    float v = fmaxf(acc[ti][tj][r] + b, 0.f);
                    s1 += v; s2 += v * v;
                }
            }
            s1 += __shfl_xor(s1, 16); s1 += __shfl_xor(s1, 32);
            s2 += __shfl_xor(s2, 16); s2 += __shfl_xor(s2, 32);
            if (lane < 16) sbuf[(wr * 2 + ep) * 128 + colL] = make_float2(s1, s2);
        }
    }
    __syncthreads();
    for (int idx = tid; idx < 512; idx += 256) {
        int ep = idx >> 7, cl = idx & 127;
        float2 pr = sbuf[ep * 128 + cl];
        float mean = pr.x * (1.f / 32.f);
        float var  = (pr.y - 32.f * mean * mean) * (1.f / 31.f);   // ddof=1
        float sd   = sqrtf(fmaxf(var, 0.f));
        int e = blockIdx.y * 4 + ep;
        int f = col0 + cl;
        Z[(size_t)e * TDIM + 1 + f]   = mean;
        Z[(size_t)e * TDIM + 514 + f] = sd;
        Zb[(size_t)e * KP + 1 + f]    = f2bf(mean);
        Zb[(size_t)e * KP + 514 + f]  = f2bf(sd);
        if (e >= 256) {
            int j2 = e - 256;
            muT_te[(size_t)(1 + f) * 256 + j2]   = mean;
            muT_te[(size_t)(514 + f) * 256 + j2] = sd;
        }
    }
}

// ---------------- Kernel 2: targets stats + Zb pad zero + Hs_te zero ----------
__global__ __launch_bounds__(256)
void k_tgt(const float* __restrict__ Ttr, const float* __restrict__ Tte,
           float* __restrict__ Z, unsigned short* __restrict__ Zb,
           float* __restrict__ muT_te, float* __restrict__ Hs_te)
{
    if (blockIdx.x == 0) Hs_te[threadIdx.x] = 0.f;   // zeroed before k_lv_ep atomics
    int e = blockIdx.x * 256 + threadIdx.x;
    if (e >= 512) return;
    const float* p = (e < 256) ? (Ttr + (size_t)e * 32) : (Tte + (size_t)(e - 256) * 32);
    float S1 = 0.f, S2 = 0.f;
#pragma unroll
    for (int n = 0; n < 32; ++n) { float v = p[n]; S1 += v; S2 += v * v; }
    float mean = S1 * (1.f / 32.f);
    float var  = (S2 - 32.f * mean * mean) * (1.f / 31.f);
    float sd   = sqrtf(fmaxf(var, 0.f));
    Z[(size_t)e * TDIM + 0]   = mean;
    Z[(size_t)e * TDIM + 513] = sd;
    Zb[(size_t)e * KP + 0]    = f2bf(mean);
    Zb[(size_t)e * KP + 513]  = f2bf(sd);
#pragma unroll
    for (int c = TDIM; c < KP; ++c) Zb[(size_t)e * KP + c] = 0;   // K pad (ws re-poisoned)
    if (e >= 256) {
        muT_te[(size_t)0 * 256 + (e - 256)]   = mean;
        muT_te[(size_t)513 * 256 + (e - 256)] = sd;
    }
}

// ---- Kernel 3a (fast): bf16 MFMA LV GEMM, split-K=7, raw fp32 partials -------
__global__ __launch_bounds__(256)
void k_lv_mfma(const unsigned short* __restrict__ Zb,
               const unsigned short* __restrict__ Wlt,
               float* __restrict__ Cacc)
{
    __shared__ unsigned short As[128 * 40];
    __shared__ unsigned short Bs[128 * 40];

    const int tid  = threadIdx.x;
    const int lane = tid & 63;
    const int wave = tid >> 6;
    const int wr = wave >> 1, wc = wave & 1;
    const int m = lane & 15, quad = lane >> 4;
    const int col0 = blockIdx.x * 128;
    const int row0 = blockIdx.y * 128;
    const int p    = blockIdx.z;
    const int it0  = (p < 5) ? p * 5 : 25 + (p - 5) * 4;
    const int itn  = (p < 5) ? 5 : 4;

    f32x4 acc[4][4];
#pragma unroll
    for (int i = 0; i < 4; ++i)
#pragma unroll
        for (int j = 0; j < 4; ++j) acc[i][j] = (f32x4){0.f, 0.f, 0.f, 0.f};

    const int srow = tid >> 2;
    const int skc  = tid & 3;

    for (int it = it0; it < it0 + itn; ++it) {
        int k0 = it * 32;
#pragma unroll
        for (int s = 0; s < 2; ++s) {
            int row = srow + s * 64;
            uint4 va = *(const uint4*)(Zb  + (size_t)(row0 + row) * KP + k0 + skc * 8);
            uint4 vb = *(const uint4*)(Wlt + (size_t)(col0 + row) * KP + k0 + skc * 8);
            *(uint4*)(As + row * 40 + skc * 8) = va;
            *(uint4*)(Bs + row * 40 + skc * 8) = vb;
        }
        __syncthreads();
        bf16x8 af[4], bfr[4];
#pragma unroll
        for (int t2 = 0; t2 < 4; ++t2) {
            af[t2]  = *(const bf16x8*)(As + (wr * 64 + t2 * 16 + m) * 40 + quad * 8);
            bfr[t2] = *(const bf16x8*)(Bs + (wc * 64 + t2 * 16 + m) * 40 + quad * 8);
        }
#pragma unroll
        for (int ti = 0; ti < 4; ++ti)
#pragma unroll
            for (int tj = 0; tj < 4; ++tj)
                acc[ti][tj] = __builtin_amdgcn_mfma_f32_16x16x32_bf16(
                    af[ti], bfr[tj], acc[ti][tj], 0, 0, 0);
        __syncthreads();
    }

    float* C = Cacc + (size_t)p * 512 * NP;
#pragma unroll
    for (int ti = 0; ti < 4; ++ti)
#pragma unroll
        for (int tj = 0; tj < 4; ++tj) {
            int c = col0 + wc * 64 + tj * 16 + m;
#pragma unroll
            for (int r = 0; r < 4; ++r) {
                int rg = row0 + wr * 64 + ti * 16 + quad * 4 + r;
                C[(size_t)rg * NP + c] = acc[ti][tj][r];
            }
        }
}

// ---- Kernel 3b: reduce partials + bias + clip + exp; tr coalesced, te via
// LDS transpose; H per te-row via shfl + atomicAdd. Grid (33, 16), block 256.
__global__ __launch_bounds__(256)
void k_lv_ep(const float* __restrict__ Cacc, const float* __restrict__ blv,
             float* __restrict__ E_tr, float* __restrict__ R_tr,
             float* __restrict__ E_teT, float* __restrict__ R_teT,
             float* __restrict__ Hs_te)
{
    __shared__ float Et[32][33], Rt[32][33];
    const int t = threadIdx.x;
    const int rl = t >> 3;
    const int ci = t & 7;
    const int r  = blockIdx.y * 32 + rl;
    const int c0 = blockIdx.x * 32 + ci * 4;
    const bool is_te = (blockIdx.y >= 8);

    float4 s = make_float4(0.f, 0.f, 0.f, 0.f);
#pragma unroll
    for (int p = 0; p < KSPLIT; ++p) {
        float4 v = *(const float4*)(Cacc + (size_t)p * 512 * NP + (size_t)r * NP + c0);
        s.x += v.x; s.y += v.y; s.z += v.z; s.w += v.w;
    }
    float sv[4] = {s.x, s.y, s.z, s.w};
    float lv[4], E[4], R[4];
#pragma unroll
    for (int q = 0; q < 4; ++q) {
        int c = c0 + q;
        float b = (c < TDIM) ? blv[c] : 0.f;
        float x = fminf(fmaxf(sv[q] + b, -9.f), -2.f);
        lv[q] = x; E[q] = expf(x); R[q] = expf(-x);
    }

    if (!is_te) {
        if (c0 + 1 < TDIM) {
            *(float2*)(E_tr + (size_t)r * TDIM + c0) = make_float2(E[0], E[1]);
            *(float2*)(R_tr + (size_t)r * TDIM + c0) = make_float2(R[0], R[1]);
        }
        if (c0 + 3 < TDIM) {
            *(float2*)(E_tr + (size_t)r * TDIM + c0 + 2) = make_float2(E[2], E[3]);
            *(float2*)(R_tr + (size_t)r * TDIM + c0 + 2) = make_float2(R[2], R[3]);
        }
    } else {
        float h = 0.f;
#pragma unroll
        for (int q = 0; q < 4; ++q) {
            Et[ci * 4 + q][rl] = E[q];
            Rt[ci * 4 + q][rl] = R[q];
            if (c0 + q < TDIM) h += lv[q];
        }
        h += __shfl_xor(h, 1); h += __shfl_xor(h, 2); h += __shfl_xor(h, 4);
        if (ci == 0) atomicAdd(Hs_te + (r - 256), h);
        __syncthreads();
        int cl = t >> 3, ri = (t & 7) * 4;
        int c = blockIdx.x * 32 + cl;
        if (c < TDIM) {
            int rbase = (blockIdx.y - 8) * 32 + ri;
            *(float4*)(E_teT + (size_t)c * 256 + rbase) =
                make_float4(Et[cl][ri], Et[cl][ri + 1], Et[cl][ri + 2], Et[cl][ri + 3]);
            *(float4*)(R_teT + (size_t)c * 256 + rbase) =
                make_float4(Rt[cl][ri], Rt[cl][ri + 1], Rt[cl][ri + 2], Rt[cl][ri + 3]);
        }
    }
}

// ---- Fallback fp32 kernels (ws too small) ------------------------------------
__global__ __launch_bounds__(256)
void k_lv(const float* __restrict__ Z, const float* __restrict__ Wlv,
          const float* __restrict__ blv,
          float* __restrict__ E_tr, float* __restrict__ R_tr,
          float* __restrict__ E_teT, float* __restrict__ R_teT,
          float* __restrict__ Hs_te)
{
    __shared__ float Ast[16 * 68];
    __shared__ float Bs[16 * 68];
    const int tid = threadIdx.x;
    const int tx = tid & 15;
    const int ty = tid >> 4;
    const int col0 = blockIdx.x * 64;
    const int row0 = blockIdx.y * 64;

    float acc[4][4];
#pragma unroll
    for (int i = 0; i < 4; ++i)
#pragma unroll
        for (int j = 0; j < 4; ++j) acc[i][j] = 0.f;

    for (int k0 = 0; k0 < TDIM; k0 += 16) {
        {
            int row = tid >> 2, kp = tid & 3;
            const float* src = Z + (size_t)(row0 + row) * TDIM + k0 + kp * 4;
            float x0 = 0.f, x1 = 0.f, x2 = 0.f, x3 = 0.f;
            if (k0 + kp * 4 + 1 < TDIM) { float2 v = *(const float2*)(src);     x0 = v.x; x1 = v.y; }
            if (k0 + kp * 4 + 3 < TDIM) { float2 v = *(const float2*)(src + 2); x2 = v.x; x3 = v.y; }
            Ast[(kp * 4 + 0) * 68 + row] = x0;
            Ast[(kp * 4 + 1) * 68 + row] = x1;
            Ast[(kp * 4 + 2) * 68 + row] = x2;
            Ast[(kp * 4 + 3) * 68 + row] = x3;
        }
        {
            int kk = tid >> 4, cg = tid & 15;
#pragma unroll
            for (int c = 0; c < 4; ++c) {
                int col = col0 + cg * 4 + c;
                float v = 0.f;
                if (k0 + kk < TDIM && col < TDIM)
                    v = Wlv[(size_t)(k0 + kk) * TDIM + col];
                Bs[kk * 68 + cg * 4 + c] = v;
            }
        }
        __syncthreads();
#pragma unroll
        for (int kk = 0; kk < 16; ++kk) {
            float4 a = *(const float4*)(Ast + kk * 68 + ty * 4);
            float4 b = *(const float4*)(Bs + kk * 68 + tx * 4);
            float av[4] = {a.x, a.y, a.z, a.w};
            float bv[4] = {b.x, b.y, b.z, b.w};
#pragma unroll
            for (int i = 0; i < 4; ++i)
#pragma unroll
                for (int j = 0; j < 4; ++j)
                    acc[i][j] = fmaf(av[i], bv[j], acc[i][j]);
        }
        __syncthreads();
    }

    float hpart[4] = {0.f, 0.f, 0.f, 0.f};
#pragma unroll
    for (int i = 0; i < 4; ++i) {
        int r = row0 + ty * 4 + i;
#pragma unroll
        for (int j = 0; j < 4; ++j) {
            int c = col0 + tx * 4 + j;
            if (c < TDIM) {
                float lv = acc[i][j] + blv[c];
                lv = fminf(fmaxf(lv, -9.f), -2.f);
                float E = expf(lv);
                float R = expf(-lv);
                if (r < 256) {
                    E_tr[(size_t)r * TDIM + c] = E;
                    R_tr[(size_t)r * TDIM + c] = R;
                } else {
                    E_teT[(size_t)c * 256 + (r - 256)] = E;
                    R_teT[(size_t)c * 256 + (r - 256)] = R;
                    hpart[i] += lv;
                }
            }
        }
    }
    if (row0 >= 256) {
        __syncthreads();
        float* hbuf = Ast;
#pragma unroll
        for (int i = 0; i < 4; ++i) hbuf[(ty * 4 + i) * 16 + tx] = hpart[i];
        __syncthreads();
        if (tid < 64) {
            float s = 0.f;
#pragma unroll
            for (int x = 0; x < 16; ++x) s += hbuf[tid * 16 + x];
            atomicAdd(Hs_te + (row0 - 256 + tid), s);
        }
    }
}

__global__ __launch_bounds__(256)
void k_fe_f32(const float* __restrict__ Atr, const float* __restrict__ Ate,
              const float* __restrict__ Wfe, const float* __restrict__ bfe,
              float* __restrict__ Z, float* __restrict__ muT_te)
{
    __shared__ float lds[4224];
    float* Ast = lds;
    float* Bs  = lds + 2112;

    const int tid = threadIdx.x;
    const int tx = tid & 15;
    const int ty = tid >> 4;
    const int col0 = blockIdx.x * 128;
    const int row0 = blockIdx.y * 128;
    const float* A = (row0 < 8192) ? Atr : Ate;
    const int ar0 = (row0 < 8192) ? row0 : (row0 - 8192);

    float acc[8][8];
#pragma unroll
    for (int i = 0; i < 8; ++i)
#pragma unroll
        for (int j = 0; j < 8; ++j) acc[i][j] = 0.f;

    for (int k0 = 0; k0 < 512; k0 += 16) {
#pragma unroll
        for (int s = 0; s < 2; ++s) {
            int u = tid + s * 256;
            int row = u >> 2, q = u & 3;
            float4 v = *(const float4*)(A + (size_t)(ar0 + row) * 512 + k0 + q * 4);
            Ast[(q * 4 + 0) * 132 + row] = v.x;
            Ast[(q * 4 + 1) * 132 + row] = v.y;
            Ast[(q * 4 + 2) * 132 + row] = v.z;
            Ast[(q * 4 + 3) * 132 + row] = v.w;
        }
#pragma unroll
        for (int s = 0; s < 2; ++s) {
            int u = tid + s * 256;
            int kk = u >> 5, c8 = u & 31;
            float4 v = *(const float4*)(Wfe + (size_t)(k0 + kk) * 512 + col0 + c8 * 4);
            *(float4*)(Bs + kk * 132 + c8 * 4) = v;
        }
        __syncthreads();
#pragma unroll
        for (int kk = 0; kk < 16; ++kk) {
            float4 a0 = *(const float4*)(Ast + kk * 132 + ty * 8);
            float4 a1 = *(const float4*)(Ast + kk * 132 + ty * 8 + 4);
            float4 b0 = *(const float4*)(Bs + kk * 132 + tx * 4);
            float4 b1 = *(const float4*)(Bs + kk * 132 + 64 + tx * 4);
            float av[8] = {a0.x, a0.y, a0.z, a0.w, a1.x, a1.y, a1.z, a1.w};
            float bv[8] = {b0.x, b0.y, b0.z, b0.w, b1.x, b1.y, b1.z, b1.w};
#pragma unroll
            for (int i = 0; i < 8; ++i)
#pragma unroll
                for (int j = 0; j < 8; ++j)
                    acc[i][j] = fmaf(av[i], bv[j], acc[i][j]);
        }
        __syncthreads();
    }

    float2* sbuf = (float2*)lds;
#pragma unroll
    for (int j = 0; j < 8; ++j) {
        int cl = (j < 4) ? (tx * 4 + j) : (64 + tx * 4 + (j - 4));
        float b = bfe[col0 + cl];
        float s1 = 0.f, s2 = 0.f;
#pragma unroll
        for (int i = 0; i < 8; ++i) {
            float v = acc[i][j] + b;
            v = fmaxf(v, 0.f);
            s1 += v; s2 += v * v;
        }
        sbuf[ty * 128 + cl] = make_float2(s1, s2);
    }
    __syncthreads();
    for (int idx = tid; idx < 512; idx += 256) {
        int ep = idx >> 7, cl = idx & 127;
        float S1 = 0.f, S2 = 0.f;
#pragma unroll
        for (int q = 0; q < 4; ++q) {
            float2 p = sbuf[(ep * 4 + q) * 128 + cl];
            S1 += p.x; S2 += p.y;
        }
        float mean = S1 * (1.f / 32.f);
        float var  = (S2 - 32.f * mean * mean) * (1.f / 31.f);
        float sd   = sqrtf(fmaxf(var, 0.f));
        int e = (row0 >> 5) + ep;
        int f = col0 + cl;
        Z[(size_t)e * TDIM + 1 + f]   = mean;
        Z[(size_t)e * TDIM + 514 + f] = sd;
        if (e >= 256) {
            int j2 = e - 256;
            muT_te[(size_t)(1 + f) * 256 + j2]   = mean;
            muT_te[(size_t)(514 + f) * 256 + j2] = sd;
        }
    }
}

__global__ __launch_bounds__(256)
void k_tgt_f32(const float* __restrict__ Ttr, const float* __restrict__ Tte,
               float* __restrict__ Z, float* __restrict__ muT_te,
               float* __restrict__ Hs_te)
{
    if (blockIdx.x == 0) Hs_te[threadIdx.x] = 0.f;
    int e = blockIdx.x * 256 + threadIdx.x;
    if (e >= 512) return;
    const float* p = (e < 256) ? (Ttr + (size_t)e * 32) : (Tte + (size_t)(e - 256) * 32);
    float S1 = 0.f, S2 = 0.f;
#pragma unroll
    for (int n = 0; n < 32; ++n) { float v = p[n]; S1 += v; S2 += v * v; }
    float mean = S1 * (1.f / 32.f);
    float var  = (S2 - 32.f * mean * mean) * (1.f / 31.f);
    float sd   = sqrtf(fmaxf(var, 0.f));
    Z[(size_t)e * TDIM + 0]   = mean;
    Z[(size_t)e * TDIM + 513] = sd;
    if (e >= 256) {
        muT_te[(size_t)0 * 256 + (e - 256)]   = mean;
        muT_te[(size_t)513 * 256 + (e - 256)] = sd;
    }
}

// ---------------- Kernel 4: pairwise partial sums -----------------------------
#define TCH 65
__global__ __launch_bounds__(256)
void k_pair(const float* __restrict__ Z, const float* __restrict__ E_tr,
            const float* __restrict__ R_tr, const float* __restrict__ muT_te,
            const float* __restrict__ E_teT, const float* __restrict__ R_teT,
            float* __restrict__ Sp)
{
    __shared__ float Lm[8 * 68], Le[8 * 68], Lr[8 * 68];
    const int tid = threadIdx.x;
    const int i0 = blockIdx.x * 8;
    const int t0 = blockIdx.y * TCH;
    const int tlen = min(TCH, TDIM - t0);

    if (tid < tlen) {
#pragma unroll
        for (int r = 0; r < 8; ++r) {
            size_t off = (size_t)(i0 + r) * TDIM + t0 + tid;
            Lm[r * 68 + tid] = Z[off];
            Le[r * 68 + tid] = E_tr[off];
            Lr[r * 68 + tid] = R_tr[off];
        }
    }
    __syncthreads();

    float S[8];
#pragma unroll
    for (int r = 0; r < 8; ++r) S[r] = 0.f;
    const int j = tid;
    for (int tt = 0; tt < tlen; ++tt) {
        size_t o = (size_t)(t0 + tt) * 256 + j;
        float m2 = muT_te[o], e2 = E_teT[o], r2 = R_teT[o];
#pragma unroll
        for (int r = 0; r < 8; ++r) {
            float m1 = Lm[r * 68 + tt];
            float e1 = Le[r * 68 + tt];
            float r1 = Lr[r * 68 + tt];
            float d = m1 - m2;
            S[r] += e1 * r2 + e2 * r1 + d * d * (r1 + r2);
        }
    }
#pragma unroll
    for (int r = 0; r < 8; ++r)
        Sp[((size_t)blockIdx.y * 256 + i0 + r) * 256 + j] = S[r];
}

// ---------------- Kernel 5: row log_softmax + classes -------------------------
__global__ __launch_bounds__(256)
void k_soft(const float* __restrict__ Sp, const float* __restrict__ Hs_te,
            float* __restrict__ outp)
{
    __shared__ float red[4], red2[4];
    const int i = blockIdx.x, j = threadIdx.x;
    float s = 0.f;
#pragma unroll
    for (int tc = 0; tc < 16; ++tc)
        s += Sp[((size_t)tc * 256 + i) * 256 + j];
    float v = -(0.5f * s + Hs_te[j]);

    float m = v;
#pragma unroll
    for (int o = 32; o > 0; o >>= 1) m = fmaxf(m, __shfl_xor(m, o));
    if ((j & 63) == 0) red[j >> 6] = m;
    __syncthreads();
    m = fmaxf(fmaxf(red[0], red[1]), fmaxf(red[2], red[3]));

    float p = v - m;
    float t = expf(p);
#pragma unroll
    for (int o = 32; o > 0; o >>= 1) t += __shfl_xor(t, o);
    if ((j & 63) == 0) red2[j >> 6] = t;
    __syncthreads();
    t = red2[0] + red2[1] + red2[2] + red2[3];

    outp[(size_t)i * 256 + j] = p - logf(t);
    if (i == 0) outp[65536 + j] = (float)j;
}

extern "C" void kernel_launch(void* const* d_in, const int* in_sizes, int n_in,
                              void* d_out, int out_size, void* d_ws, size_t ws_size,
                              hipStream_t stream)
{
    const float* tri = (const float*)d_in[0];
    const float* trt = (const float*)d_in[1];
    const float* tei = (const float*)d_in[2];
    const float* tet = (const float*)d_in[3];
    const float* Wfe = (const float*)d_in[4];
    const float* bfe = (const float*)d_in[5];
    const float* Wlv = (const float*)d_in[6];
    const float* blv = (const float*)d_in[7];
    float* outp = (float*)d_out;

    float* Z     = (float*)d_ws;                 // 512*1026 fp32
    float* E_tr  = Z + (size_t)512 * TDIM;
    float* R_tr  = E_tr + (size_t)256 * TDIM;
    float* muT   = R_tr + (size_t)256 * TDIM;
    float* E_teT = muT + (size_t)TDIM * 256;
    float* R_teT = E_teT + (size_t)TDIM * 256;
    float* Hs_te = R_teT + (size_t)TDIM * 256;   // 256
    float* Sp    = Hs_te + 256;                  // 16*256*256 fp32 = 4,194,304 B
    float* endf  = Sp + (size_t)16 * 256 * 256;  // ws + 11,549,696 B

    // Wlt/Zb alias the Sp region (consumed by LV path before k_pair writes Sp).
    unsigned short* Wlt = (unsigned short*)Sp;                       // NP*KP bf16 = 2,433,024 B
    unsigned short* Zb  = (unsigned short*)((char*)Sp + 2433024);    // 512*KP bf16 = 1,081,344 B
    // Cacc (split-K partials) + Wt in the tail region.
    float* Cacc = (float*)endf;                                      // 7*512*1152*4 = 16,515,072 B
    unsigned short* Wt = (unsigned short*)((char*)endf + 16515072);  // 512*512 bf16 = 524,288 B

    const size_t need = 11549696ull + 16515072ull + 524288ull;       // 28,589,056 B
    const bool fast = (ws_size >= need);

    if (fast) {
        k_cvtboth<<<dim3(36, 33, 2), 256, 0, stream>>>(Wfe, Wlv, Wt, Wlt);
        k_fe_mfma<<<dim3(4, 128), 256, 0, stream>>>(tri, tei, Wt, bfe, Z, Zb, muT);
        k_tgt    <<<2, 256, 0, stream>>>(trt, tet, Z, Zb, muT, Hs_te);
        k_lv_mfma<<<dim3(9, 4, KSPLIT), 256, 0, stream>>>(Zb, Wlt, Cacc);
        k_lv_ep  <<<dim3(33, 16), 256, 0, stream>>>(Cacc, blv, E_tr, R_tr, E_teT, R_teT, Hs_te);
    } else {
        k_fe_f32 <<<dim3(4, 128), 256, 0, stream>>>(tri, tei, Wfe, bfe, Z, muT);
        k_tgt_f32<<<2, 256, 0, stream>>>(trt, tet, Z, muT, Hs_te);
        k_lv     <<<dim3(17, 8), 256, 0, stream>>>(Z, Wlv, blv, E_tr, R_tr, E_teT, R_teT, Hs_te);
    }
    k_pair<<<dim3(32, 16), 256, 0, stream>>>(Z, E_tr, R_tr, muT, E_teT, R_teT, Sp);
    k_soft<<<256, 256, 0, stream>>>(Sp, Hs_te, outp);
}

// Round 6
// 157.567 us; speedup vs baseline: 1.1073x; 1.1073x over previous
//
#include <hip/hip_runtime.h>
#include <math.h>

#define TDIM 1026
#define KP 1056          // K padded for LV GEMM (33 * 32)
#define NP 1152          // N padded for LV GEMM (9 * 128)
#define KSPLIT 7
#define KK 4224          // pairwise GEMM K: 4 components x 1056

typedef __attribute__((ext_vector_type(8))) short bf16x8;
typedef __attribute__((ext_vector_type(4))) float f32x4;

// ---- fp32 -> bf16 RNE helpers ------------------------------------------------
__device__ inline unsigned int pk_bf16(float a, float b) {
    unsigned int ua = __float_as_uint(a), ub = __float_as_uint(b);
    ua = (ua + 0x7FFFu + ((ua >> 16) & 1u)) >> 16;
    ub = (ub + 0x7FFFu + ((ub >> 16) & 1u)) & 0xFFFF0000u;
    return ua | ub;
}
__device__ inline unsigned short f2bf(float a) {
    unsigned int ua = __float_as_uint(a);
    return (unsigned short)((ua + 0x7FFFu + ((ua >> 16) & 1u)) >> 16);
}

// ---- convert + transpose both weight matrices to bf16 [n][k] -----------------
__global__ __launch_bounds__(256)
void k_cvtboth(const float* __restrict__ Wfe, const float* __restrict__ Wlv,
               unsigned short* __restrict__ Wt, unsigned short* __restrict__ Wlt)
{
    __shared__ float T[32][33];
    const int z = blockIdx.z;
    if (z && (blockIdx.x >= 16 || blockIdx.y >= 16)) return;
    const float* W = z ? Wfe : Wlv;
    unsigned short* D = z ? Wt : Wlt;
    const int S  = z ? 512 : TDIM;
    const int DS = z ? 512 : KP;
    const int n0 = blockIdx.x * 32, k0 = blockIdx.y * 32;
    const int t = threadIdx.x;
    {
        int ky = t >> 3, nx = (t & 7) * 4;
#pragma unroll
        for (int i = 0; i < 4; ++i) {
            float v = 0.f;
            if (k0 + ky < S && n0 + nx + i < S)
                v = W[(size_t)(k0 + ky) * S + n0 + nx + i];
            T[nx + i][ky] = v;
        }
    }
    __syncthreads();
    {
        int ny = t >> 3, kx = (t & 7) * 4;
        ushort4 o;
        o.x = f2bf(T[ny][kx + 0]); o.y = f2bf(T[ny][kx + 1]);
        o.z = f2bf(T[ny][kx + 2]); o.w = f2bf(T[ny][kx + 3]);
        *(ushort4*)(D + (size_t)(n0 + ny) * DS + k0 + kx) = o;
    }
}

// ---- Kernel 1: bf16 MFMA FE GEMM (fused fp32->bf16 A), pipelined; stats ------
__global__ __launch_bounds__(256)
void k_fe_mfma(const float* __restrict__ Atr, const float* __restrict__ Ate,
               const unsigned short* __restrict__ Wt,
               const float* __restrict__ bfe, float* __restrict__ Z,
               unsigned short* __restrict__ Zb)
{
    __shared__ unsigned short As[128 * 40];
    __shared__ unsigned short Bs[128 * 40];
    __shared__ float2 sbuf[4 * 128];

    const int tid  = threadIdx.x;
    const int lane = tid & 63;
    const int wave = tid >> 6;
    const int wr = wave >> 1, wc = wave & 1;
    const int m = lane & 15, quad = lane >> 4;
    const int col0 = blockIdx.x * 128;
    const int row0 = blockIdx.y * 128;
    const float* A = (row0 < 8192) ? Atr : Ate;
    const int ar0 = row0 & 8191;

    f32x4 acc[4][4];
#pragma unroll
    for (int i = 0; i < 4; ++i)
#pragma unroll
        for (int j = 0; j < 4; ++j) acc[i][j] = (f32x4){0.f, 0.f, 0.f, 0.f};

    const int srow = tid >> 2;
    const int skc  = tid & 3;

    float4 pa0[2], pa1[2];
    uint4  pb[2];

#define FE_PRELOAD(K0)                                                              \
    {                                                                               \
        _Pragma("unroll")                                                           \
        for (int s = 0; s < 2; ++s) {                                               \
            int row = srow + s * 64;                                                \
            const float* ap = A + (size_t)(ar0 + row) * 512 + (K0) + skc * 8;       \
            pa0[s] = *(const float4*)(ap);                                          \
            pa1[s] = *(const float4*)(ap + 4);                                      \
            pb[s]  = *(const uint4*)(Wt + (size_t)(col0 + row) * 512 + (K0) + skc * 8); \
        }                                                                           \
    }

    FE_PRELOAD(0)
    for (int k0 = 0; k0 < 512; k0 += 32) {
        __syncthreads();
#pragma unroll
        for (int s = 0; s < 2; ++s) {
            int row = srow + s * 64;
            uint4 va;
            va.x = pk_bf16(pa0[s].x, pa0[s].y); va.y = pk_bf16(pa0[s].z, pa0[s].w);
            va.z = pk_bf16(pa1[s].x, pa1[s].y); va.w = pk_bf16(pa1[s].z, pa1[s].w);
            *(uint4*)(As + row * 40 + skc * 8) = va;
            *(uint4*)(Bs + row * 40 + skc * 8) = pb[s];
        }
        __syncthreads();
        if (k0 + 32 < 512) FE_PRELOAD(k0 + 32)
        bf16x8 af[4], bfr[4];
#pragma unroll
        for (int t2 = 0; t2 < 4; ++t2) {
            af[t2]  = *(const bf16x8*)(As + (wr * 64 + t2 * 16 + m) * 40 + quad * 8);
            bfr[t2] = *(const bf16x8*)(Bs + (wc * 64 + t2 * 16 + m) * 40 + quad * 8);
        }
#pragma unroll
        for (int ti = 0; ti < 4; ++ti)
#pragma unroll
            for (int tj = 0; tj < 4; ++tj)
                acc[ti][tj] = __builtin_amdgcn_mfma_f32_16x16x32_bf16(
                    af[ti], bfr[tj], acc[ti][tj], 0, 0, 0);
    }

#pragma unroll
    for (int ep = 0; ep < 2; ++ep) {
#pragma unroll
        for (int tj = 0; tj < 4; ++tj) {
            int colL = wc * 64 + tj * 16 + m;
            float b = bfe[col0 + colL];
            float s1 = 0.f, s2 = 0.f;
#pragma unroll
            for (int p = 0; p < 2; ++p) {
                int ti = ep * 2 + p;
#pragma unroll
                for (int r = 0; r < 4; ++r) {
                    float v = fmaxf(acc[ti][tj][r] + b, 0.f);
                    s1 += v; s2 += v * v;
                }
            }
            s1 += __shfl_xor(s1, 16); s1 += __shfl_xor(s1, 32);
            s2 += __shfl_xor(s2, 16); s2 += __shfl_xor(s2, 32);
            if (lane < 16) sbuf[(wr * 2 + ep) * 128 + colL] = make_float2(s1, s2);
        }
    }
    __syncthreads();
    for (int idx = tid; idx < 512; idx += 256) {
        int ep = idx >> 7, cl = idx & 127;
        float2 pr = sbuf[ep * 128 + cl];
        float mean = pr.x * (1.f / 32.f);
        float var  = (pr.y - 32.f * mean * mean) * (1.f / 31.f);   // ddof=1
        float sd   = sqrtf(fmaxf(var, 0.f));
        int e = blockIdx.y * 4 + ep;
        int f = col0 + cl;
        Z[(size_t)e * TDIM + 1 + f]   = mean;
        Z[(size_t)e * TDIM + 514 + f] = sd;
        Zb[(size_t)e * KP + 1 + f]    = f2bf(mean);
        Zb[(size_t)e * KP + 514 + f]  = f2bf(sd);
    }
}

// ---------------- Kernel 2: targets stats + Zb pad + Hs/cterm zero ------------
__global__ __launch_bounds__(256)
void k_tgt(const float* __restrict__ Ttr, const float* __restrict__ Tte,
           float* __restrict__ Z, unsigned short* __restrict__ Zb,
           float* __restrict__ Hs_te, float* __restrict__ cterm)
{
    if (blockIdx.x == 0) { Hs_te[threadIdx.x] = 0.f; cterm[threadIdx.x] = 0.f; }
    int e = blockIdx.x * 256 + threadIdx.x;
    if (e >= 512) return;
    const float* p = (e < 256) ? (Ttr + (size_t)e * 32) : (Tte + (size_t)(e - 256) * 32);
    float S1 = 0.f, S2 = 0.f;
#pragma unroll
    for (int n = 0; n < 32; ++n) { float v = p[n]; S1 += v; S2 += v * v; }
    float mean = S1 * (1.f / 32.f);
    float var  = (S2 - 32.f * mean * mean) * (1.f / 31.f);
    float sd   = sqrtf(fmaxf(var, 0.f));
    Z[(size_t)e * TDIM + 0]   = mean;
    Z[(size_t)e * TDIM + 513] = sd;
    Zb[(size_t)e * KP + 0]    = f2bf(mean);
    Zb[(size_t)e * KP + 513]  = f2bf(sd);
#pragma unroll
    for (int c = TDIM; c < KP; ++c) Zb[(size_t)e * KP + c] = 0;   // K pad
}

// ---- Kernel 3a: bf16 MFMA LV GEMM, split-K=7, raw fp32 partials --------------
__global__ __launch_bounds__(256)
void k_lv_mfma(const unsigned short* __restrict__ Zb,
               const unsigned short* __restrict__ Wlt,
               float* __restrict__ Cacc)
{
    __shared__ unsigned short As[128 * 40];
    __shared__ unsigned short Bs[128 * 40];

    const int tid  = threadIdx.x;
    const int lane = tid & 63;
    const int wave = tid >> 6;
    const int wr = wave >> 1, wc = wave & 1;
    const int m = lane & 15, quad = lane >> 4;
    const int col0 = blockIdx.x * 128;
    const int row0 = blockIdx.y * 128;
    const int p    = blockIdx.z;
    const int it0  = (p < 5) ? p * 5 : 25 + (p - 5) * 4;
    const int itn  = (p < 5) ? 5 : 4;

    f32x4 acc[4][4];
#pragma unroll
    for (int i = 0; i < 4; ++i)
#pragma unroll
        for (int j = 0; j < 4; ++j) acc[i][j] = (f32x4){0.f, 0.f, 0.f, 0.f};

    const int srow = tid >> 2;
    const int skc  = tid & 3;

    for (int it = it0; it < it0 + itn; ++it) {
        int k0 = it * 32;
#pragma unroll
        for (int s = 0; s < 2; ++s) {
            int row = srow + s * 64;
            uint4 va = *(const uint4*)(Zb  + (size_t)(row0 + row) * KP + k0 + skc * 8);
            uint4 vb = *(const uint4*)(Wlt + (size_t)(col0 + row) * KP + k0 + skc * 8);
            *(uint4*)(As + row * 40 + skc * 8) = va;
            *(uint4*)(Bs + row * 40 + skc * 8) = vb;
        }
        __syncthreads();
        bf16x8 af[4], bfr[4];
#pragma unroll
        for (int t2 = 0; t2 < 4; ++t2) {
            af[t2]  = *(const bf16x8*)(As + (wr * 64 + t2 * 16 + m) * 40 + quad * 8);
            bfr[t2] = *(const bf16x8*)(Bs + (wc * 64 + t2 * 16 + m) * 40 + quad * 8);
        }
#pragma unroll
        for (int ti = 0; ti < 4; ++ti)
#pragma unroll
            for (int tj = 0; tj < 4; ++tj)
                acc[ti][tj] = __builtin_amdgcn_mfma_f32_16x16x32_bf16(
                    af[ti], bfr[tj], acc[ti][tj], 0, 0, 0);
        __syncthreads();
    }

    float* C = Cacc + (size_t)p * 512 * NP;
#pragma unroll
    for (int ti = 0; ti < 4; ++ti)
#pragma unroll
        for (int tj = 0; tj < 4; ++tj) {
            int c = col0 + wc * 64 + tj * 16 + m;
#pragma unroll
            for (int r = 0; r < 4; ++r) {
                int rg = row0 + wr * 64 + ti * 16 + quad * 4 + r;
                C[(size_t)rg * NP + c] = acc[ti][tj][r];
            }
        }
}

// ---- Kernel 3b: reduce partials + bias/clip/exp; build pairwise-GEMM operands
// X[i] = [e1+m1^2, r1, -2*m1*r1, -2*m1], Y[j] = [r2, e2+m2^2, m2, m2*r2]
// (interleaved 4/t, KK=4224, zero-padded). H and cterm = sum m2^2*r2 via atomics.
__global__ __launch_bounds__(256)
void k_lv_ep(const float* __restrict__ Cacc, const float* __restrict__ Zf,
             const float* __restrict__ blv,
             unsigned short* __restrict__ Xb, unsigned short* __restrict__ Yb,
             float* __restrict__ Hs_te, float* __restrict__ cterm)
{
    const int t = threadIdx.x;
    const int rl = t >> 3;            // 0..31
    const int ci = t & 7;             // 0..7 -> 4 cols each
    const int r  = blockIdx.y * 32 + rl;          // 0..511
    const int c0 = blockIdx.x * 32 + ci * 4;      // 0..1055
    const bool is_te = (r >= 256);

    float4 s = make_float4(0.f, 0.f, 0.f, 0.f);
#pragma unroll
    for (int p = 0; p < KSPLIT; ++p) {
        float4 v = *(const float4*)(Cacc + (size_t)p * 512 * NP + (size_t)r * NP + c0);
        s.x += v.x; s.y += v.y; s.z += v.z; s.w += v.w;
    }
    float sv[4] = {s.x, s.y, s.z, s.w};

    unsigned short* O = is_te ? (Yb + (size_t)(r - 256) * KK) : (Xb + (size_t)r * KK);
    float h = 0.f, ct = 0.f;
#pragma unroll
    for (int q = 0; q < 4; ++q) {
        int c = c0 + q;
        bool cok = (c < TDIM);
        ushort4 o = make_ushort4(0, 0, 0, 0);
        if (cok) {
            float x = fminf(fmaxf(sv[q] + blv[c], -9.f), -2.f);
            float E = expf(x);
            float R = expf(-x);
            float mm = Zf[(size_t)r * TDIM + c];
            if (!is_te) {
                o.x = f2bf(E + mm * mm);
                o.y = f2bf(R);
                o.z = f2bf(-2.f * mm * R);
                o.w = f2bf(-2.f * mm);
            } else {
                o.x = f2bf(R);
                o.y = f2bf(E + mm * mm);
                o.z = f2bf(mm);
                o.w = f2bf(mm * R);
                h  += x;
                ct += mm * mm * R;
            }
        }
        *(ushort4*)(O + 4 * c) = o;
    }
    if (is_te) {
        h  += __shfl_xor(h, 1);  h  += __shfl_xor(h, 2);  h  += __shfl_xor(h, 4);
        ct += __shfl_xor(ct, 1); ct += __shfl_xor(ct, 2); ct += __shfl_xor(ct, 4);
        if (ci == 0) {
            atomicAdd(Hs_te + (r - 256), h);
            atomicAdd(cterm + (r - 256), ct);
        }
    }
}

// ---- Kernel 4: pairwise GEMM S = X * Y^T, 256x256xKK bf16, split-K=16 --------
// Writes Sp[p][i][j] (same layout k_soft already reduces).
__global__ __launch_bounds__(256)
void k_pgemm(const unsigned short* __restrict__ Xb,
             const unsigned short* __restrict__ Yb,
             float* __restrict__ Sp)
{
    __shared__ unsigned short As[128 * 40];
    __shared__ unsigned short Bs[128 * 40];

    const int tid  = threadIdx.x;
    const int lane = tid & 63;
    const int wave = tid >> 6;
    const int wr = wave >> 1, wc = wave & 1;
    const int m = lane & 15, quad = lane >> 4;
    const int col0 = blockIdx.x * 128;
    const int row0 = blockIdx.y * 128;
    const int p    = blockIdx.z;           // 0..15; 132 iters = 4*9 + 12*8
    const int it0  = (p < 4) ? p * 9 : 36 + (p - 4) * 8;
    const int itn  = (p < 4) ? 9 : 8;

    f32x4 acc[4][4];
#pragma unroll
    for (int i = 0; i < 4; ++i)
#pragma unroll
        for (int j = 0; j < 4; ++j) acc[i][j] = (f32x4){0.f, 0.f, 0.f, 0.f};

    const int srow = tid >> 2;
    const int skc  = tid & 3;

    for (int it = it0; it < it0 + itn; ++it) {
        int k0 = it * 32;
#pragma unroll
        for (int s = 0; s < 2; ++s) {
            int row = srow + s * 64;
            uint4 va = *(const uint4*)(Xb + (size_t)(row0 + row) * KK + k0 + skc * 8);
            uint4 vb = *(const uint4*)(Yb + (size_t)(col0 + row) * KK + k0 + skc * 8);
            *(uint4*)(As + row * 40 + skc * 8) = va;
            *(uint4*)(Bs + row * 40 + skc * 8) = vb;
        }
        __syncthreads();
        bf16x8 af[4], bfr[4];
#pragma unroll
        for (int t2 = 0; t2 < 4; ++t2) {
            af[t2]  = *(const bf16x8*)(As + (wr * 64 + t2 * 16 + m) * 40 + quad * 8);
            bfr[t2] = *(const bf16x8*)(Bs + (wc * 64 + t2 * 16 + m) * 40 + quad * 8);
        }
#pragma unroll
        for (int ti = 0; ti < 4; ++ti)
#pragma unroll
            for (int tj = 0; tj < 4; ++tj)
                acc[ti][tj] = __builtin_amdgcn_mfma_f32_16x16x32_bf16(
                    af[ti], bfr[tj], acc[ti][tj], 0, 0, 0);
        __syncthreads();
    }

    float* C = Sp + (size_t)p * 65536;
#pragma unroll
    for (int ti = 0; ti < 4; ++ti)
#pragma unroll
        for (int tj = 0; tj < 4; ++tj) {
            int c = col0 + wc * 64 + tj * 16 + m;
#pragma unroll
            for (int r = 0; r < 4; ++r) {
                int rg = row0 + wr * 64 + ti * 16 + quad * 4 + r;
                C[(size_t)rg * 256 + c] = acc[ti][tj][r];
            }
        }
}

// ---- Kernel 5: row log_softmax + classes -------------------------------------
__global__ __launch_bounds__(256)
void k_soft(const float* __restrict__ Sp, const float* __restrict__ Hs_te,
            const float* __restrict__ cterm, float* __restrict__ outp)
{
    __shared__ float red[4], red2[4];
    const int i = blockIdx.x, j = threadIdx.x;
    float s = 0.f;
#pragma unroll
    for (int tc = 0; tc < 16; ++tc)
        s += Sp[((size_t)tc * 256 + i) * 256 + j];
    float v = -(0.5f * (s + cterm[j]) + Hs_te[j]);

    float m = v;
#pragma unroll
    for (int o = 32; o > 0; o >>= 1) m = fmaxf(m, __shfl_xor(m, o));
    if ((j & 63) == 0) red[j >> 6] = m;
    __syncthreads();
    m = fmaxf(fmaxf(red[0], red[1]), fmaxf(red[2], red[3]));

    float p = v - m;
    float t = expf(p);
#pragma unroll
    for (int o = 32; o > 0; o >>= 1) t += __shfl_xor(t, o);
    if ((j & 63) == 0) red2[j >> 6] = t;
    __syncthreads();
    t = red2[0] + red2[1] + red2[2] + red2[3];

    outp[(size_t)i * 256 + j] = p - logf(t);
    if (i == 0) outp[65536 + j] = (float)j;
}

// =================== Fallback fp32 path (ws too small) ========================
__global__ __launch_bounds__(256)
void k_fe_f32(const float* __restrict__ Atr, const float* __restrict__ Ate,
              const float* __restrict__ Wfe, const float* __restrict__ bfe,
              float* __restrict__ Z, float* __restrict__ muT_te)
{
    __shared__ float lds[4224];
    float* Ast = lds;
    float* Bs  = lds + 2112;
    const int tid = threadIdx.x;
    const int tx = tid & 15;
    const int ty = tid >> 4;
    const int col0 = blockIdx.x * 128;
    const int row0 = blockIdx.y * 128;
    const float* A = (row0 < 8192) ? Atr : Ate;
    const int ar0 = (row0 < 8192) ? row0 : (row0 - 8192);

    float acc[8][8];
#pragma unroll
    for (int i = 0; i < 8; ++i)
#pragma unroll
        for (int j = 0; j < 8; ++j) acc[i][j] = 0.f;

    for (int k0 = 0; k0 < 512; k0 += 16) {
#pragma unroll
        for (int s = 0; s < 2; ++s) {
            int u = tid + s * 256;
            int row = u >> 2, q = u & 3;
            float4 v = *(const float4*)(A + (size_t)(ar0 + row) * 512 + k0 + q * 4);
            Ast[(q * 4 + 0) * 132 + row] = v.x;
            Ast[(q * 4 + 1) * 132 + row] = v.y;
            Ast[(q * 4 + 2) * 132 + row] = v.z;
            Ast[(q * 4 + 3) * 132 + row] = v.w;
        }
#pragma unroll
        for (int s = 0; s < 2; ++s) {
            int u = tid + s * 256;
            int kk = u >> 5, c8 = u & 31;
            float4 v = *(const float4*)(Wfe + (size_t)(k0 + kk) * 512 + col0 + c8 * 4);
            *(float4*)(Bs + kk * 132 + c8 * 4) = v;
        }
        __syncthreads();
#pragma unroll
        for (int kk = 0; kk < 16; ++kk) {
            float4 a0 = *(const float4*)(Ast + kk * 132 + ty * 8);
            float4 a1 = *(const float4*)(Ast + kk * 132 + ty * 8 + 4);
            float4 b0 = *(const float4*)(Bs + kk * 132 + tx * 4);
            float4 b1 = *(const float4*)(Bs + kk * 132 + 64 + tx * 4);
            float av[8] = {a0.x, a0.y, a0.z, a0.w, a1.x, a1.y, a1.z, a1.w};
            float bv[8] = {b0.x, b0.y, b0.z, b0.w, b1.x, b1.y, b1.z, b1.w};
#pragma unroll
            for (int i = 0; i < 8; ++i)
#pragma unroll
                for (int j = 0; j < 8; ++j)
                    acc[i][j] = fmaf(av[i], bv[j], acc[i][j]);
        }
        __syncthreads();
    }

    float2* sbuf = (float2*)lds;
#pragma unroll
    for (int j = 0; j < 8; ++j) {
        int cl = (j < 4) ? (tx * 4 + j) : (64 + tx * 4 + (j - 4));
        float b = bfe[col0 + cl];
        float s1 = 0.f, s2 = 0.f;
#pragma unroll
        for (int i = 0; i < 8; ++i) {
            float v = acc[i][j] + b;
            v = fmaxf(v, 0.f);
            s1 += v; s2 += v * v;
        }
        sbuf[ty * 128 + cl] = make_float2(s1, s2);
    }
    __syncthreads();
    for (int idx = tid; idx < 512; idx += 256) {
        int ep = idx >> 7, cl = idx & 127;
        float S1 = 0.f, S2 = 0.f;
#pragma unroll
        for (int q = 0; q < 4; ++q) {
            float2 p = sbuf[(ep * 4 + q) * 128 + cl];
            S1 += p.x; S2 += p.y;
        }
        float mean = S1 * (1.f / 32.f);
        float var  = (S2 - 32.f * mean * mean) * (1.f / 31.f);
        float sd   = sqrtf(fmaxf(var, 0.f));
        int e = (row0 >> 5) + ep;
        int f = col0 + cl;
        Z[(size_t)e * TDIM + 1 + f]   = mean;
        Z[(size_t)e * TDIM + 514 + f] = sd;
        if (e >= 256) {
            int j2 = e - 256;
            muT_te[(size_t)(1 + f) * 256 + j2]   = mean;
            muT_te[(size_t)(514 + f) * 256 + j2] = sd;
        }
    }
}

__global__ __launch_bounds__(256)
void k_tgt_f32(const float* __restrict__ Ttr, const float* __restrict__ Tte,
               float* __restrict__ Z, float* __restrict__ muT_te,
               float* __restrict__ Hs_te)
{
    if (blockIdx.x == 0) Hs_te[threadIdx.x] = 0.f;
    int e = blockIdx.x * 256 + threadIdx.x;
    if (e >= 512) return;
    const float* p = (e < 256) ? (Ttr + (size_t)e * 32) : (Tte + (size_t)(e - 256) * 32);
    float S1 = 0.f, S2 = 0.f;
#pragma unroll
    for (int n = 0; n < 32; ++n) { float v = p[n]; S1 += v; S2 += v * v; }
    float mean = S1 * (1.f / 32.f);
    float var  = (S2 - 32.f * mean * mean) * (1.f / 31.f);
    float sd   = sqrtf(fmaxf(var, 0.f));
    Z[(size_t)e * TDIM + 0]   = mean;
    Z[(size_t)e * TDIM + 513] = sd;
    if (e >= 256) {
        muT_te[(size_t)0 * 256 + (e - 256)]   = mean;
        muT_te[(size_t)513 * 256 + (e - 256)] = sd;
    }
}

__global__ __launch_bounds__(256)
void k_lv(const float* __restrict__ Z, const float* __restrict__ Wlv,
          const float* __restrict__ blv,
          float* __restrict__ E_tr, float* __restrict__ R_tr,
          float* __restrict__ E_teT, float* __restrict__ R_teT,
          float* __restrict__ Hs_te)
{
    __shared__ float Ast[16 * 68];
    __shared__ float Bs[16 * 68];
    const int tid = threadIdx.x;
    const int tx = tid & 15;
    const int ty = tid >> 4;
    const int col0 = blockIdx.x * 64;
    const int row0 = blockIdx.y * 64;

    float acc[4][4];
#pragma unroll
    for (int i = 0; i < 4; ++i)
#pragma unroll
        for (int j = 0; j < 4; ++j) acc[i][j] = 0.f;

    for (int k0 = 0; k0 < TDIM; k0 += 16) {
        {
            int row = tid >> 2, kp = tid & 3;
            const float* src = Z + (size_t)(row0 + row) * TDIM + k0 + kp * 4;
            float x0 = 0.f, x1 = 0.f, x2 = 0.f, x3 = 0.f;
            if (k0 + kp * 4 + 1 < TDIM) { float2 v = *(const float2*)(src);     x0 = v.x; x1 = v.y; }
            if (k0 + kp * 4 + 3 < TDIM) { float2 v = *(const float2*)(src + 2); x2 = v.x; x3 = v.y; }
            Ast[(kp * 4 + 0) * 68 + row] = x0;
            Ast[(kp * 4 + 1) * 68 + row] = x1;
            Ast[(kp * 4 + 2) * 68 + row] = x2;
            Ast[(kp * 4 + 3) * 68 + row] = x3;
        }
        {
            int kk = tid >> 4, cg = tid & 15;
#pragma unroll
            for (int c = 0; c < 4; ++c) {
                int col = col0 + cg * 4 + c;
                float v = 0.f;
                if (k0 + kk < TDIM && col < TDIM)
                    v = Wlv[(size_t)(k0 + kk) * TDIM + col];
                Bs[kk * 68 + cg * 4 + c] = v;
            }
        }
        __syncthreads();
#pragma unroll
        for (int kk = 0; kk < 16; ++kk) {
            float4 a = *(const float4*)(Ast + kk * 68 + ty * 4);
            float4 b = *(const float4*)(Bs + kk * 68 + tx * 4);
            float av[4] = {a.x, a.y, a.z, a.w};
            float bv[4] = {b.x, b.y, b.z, b.w};
#pragma unroll
            for (int i = 0; i < 4; ++i)
#pragma unroll
                for (int j = 0; j < 4; ++j)
                    acc[i][j] = fmaf(av[i], bv[j], acc[i][j]);
        }
        __syncthreads();
    }

    float hpart[4] = {0.f, 0.f, 0.f, 0.f};
#pragma unroll
    for (int i = 0; i < 4; ++i) {
        int r = row0 + ty * 4 + i;
#pragma unroll
        for (int j = 0; j < 4; ++j) {
            int c = col0 + tx * 4 + j;
            if (c < TDIM) {
                float lv = acc[i][j] + blv[c];
                lv = fminf(fmaxf(lv, -9.f), -2.f);
                float E = expf(lv);
                float R = expf(-lv);
                if (r < 256) {
                    E_tr[(size_t)r * TDIM + c] = E;
                    R_tr[(size_t)r * TDIM + c] = R;
                } else {
                    E_teT[(size_t)c * 256 + (r - 256)] = E;
                    R_teT[(size_t)c * 256 + (r - 256)] = R;
                    hpart[i] += lv;
                }
            }
        }
    }
    if (row0 >= 256) {
        __syncthreads();
        float* hbuf = Ast;
#pragma unroll
        for (int i = 0; i < 4; ++i) hbuf[(ty * 4 + i) * 16 + tx] = hpart[i];
        __syncthreads();
        if (tid < 64) {
            float s = 0.f;
#pragma unroll
            for (int x = 0; x < 16; ++x) s += hbuf[tid * 16 + x];
            atomicAdd(Hs_te + (row0 - 256 + tid), s);
        }
    }
}

#define TCH 65
__global__ __launch_bounds__(256)
void k_pair(const float* __restrict__ Z, const float* __restrict__ E_tr,
            const float* __restrict__ R_tr, const float* __restrict__ muT_te,
            const float* __restrict__ E_teT, const float* __restrict__ R_teT,
            float* __restrict__ Sp)
{
    __shared__ float Lm[8 * 68], Le[8 * 68], Lr[8 * 68];
    const int tid = threadIdx.x;
    const int i0 = blockIdx.x * 8;
    const int t0 = blockIdx.y * TCH;
    const int tlen = min(TCH, TDIM - t0);

    if (tid < tlen) {
#pragma unroll
        for (int r = 0; r < 8; ++r) {
            size_t off = (size_t)(i0 + r) * TDIM + t0 + tid;
            Lm[r * 68 + tid] = Z[off];
            Le[r * 68 + tid] = E_tr[off];
            Lr[r * 68 + tid] = R_tr[off];
        }
    }
    __syncthreads();

    float S[8];
#pragma unroll
    for (int r = 0; r < 8; ++r) S[r] = 0.f;
    const int j = tid;
    for (int tt = 0; tt < tlen; ++tt) {
        size_t o = (size_t)(t0 + tt) * 256 + j;
        float m2 = muT_te[o], e2 = E_teT[o], r2 = R_teT[o];
#pragma unroll
        for (int r = 0; r < 8; ++r) {
            float m1 = Lm[r * 68 + tt];
            float e1 = Le[r * 68 + tt];
            float r1 = Lr[r * 68 + tt];
            float d = m1 - m2;
            S[r] += e1 * r2 + e2 * r1 + d * d * (r1 + r2);
        }
    }
#pragma unroll
    for (int r = 0; r < 8; ++r)
        Sp[((size_t)blockIdx.y * 256 + i0 + r) * 256 + j] = S[r];
}

__global__ __launch_bounds__(256)
void k_soft_fb(const float* __restrict__ Sp, const float* __restrict__ Hs_te,
               float* __restrict__ outp)
{
    __shared__ float red[4], red2[4];
    const int i = blockIdx.x, j = threadIdx.x;
    float s = 0.f;
#pragma unroll
    for (int tc = 0; tc < 16; ++tc)
        s += Sp[((size_t)tc * 256 + i) * 256 + j];
    float v = -(0.5f * s + Hs_te[j]);

    float m = v;
#pragma unroll
    for (int o = 32; o > 0; o >>= 1) m = fmaxf(m, __shfl_xor(m, o));
    if ((j & 63) == 0) red[j >> 6] = m;
    __syncthreads();
    m = fmaxf(fmaxf(red[0], red[1]), fmaxf(red[2], red[3]));

    float p = v - m;
    float t = expf(p);
#pragma unroll
    for (int o = 32; o > 0; o >>= 1) t += __shfl_xor(t, o);
    if ((j & 63) == 0) red2[j >> 6] = t;
    __syncthreads();
    t = red2[0] + red2[1] + red2[2] + red2[3];

    outp[(size_t)i * 256 + j] = p - logf(t);
    if (i == 0) outp[65536 + j] = (float)j;
}

extern "C" void kernel_launch(void* const* d_in, const int* in_sizes, int n_in,
                              void* d_out, int out_size, void* d_ws, size_t ws_size,
                              hipStream_t stream)
{
    const float* tri = (const float*)d_in[0];
    const float* trt = (const float*)d_in[1];
    const float* tei = (const float*)d_in[2];
    const float* tet = (const float*)d_in[3];
    const float* Wfe = (const float*)d_in[4];
    const float* bfe = (const float*)d_in[5];
    const float* Wlv = (const float*)d_in[6];
    const float* blv = (const float*)d_in[7];
    float* outp = (float*)d_out;

    // ---- fast-path layout ----
    char* base = (char*)d_ws;
    float* Z     = (float*)base;                                   // 512*1026*4 = 2,101,248
    float* Sp    = (float*)(base + 2101248);                       // 16*256*256*4 = 4,194,304
    float* Hs_te = (float*)(base + 2101248 + 4194304);             // 1024
    float* cterm = (float*)(base + 2101248 + 4194304 + 1024);      // 1024
    float* Cacc  = (float*)(base + 6296576 + 1024);                // 7*512*1152*4 = 16,515,072
    unsigned short* Wt = (unsigned short*)(base + 6297600 + 16515072);   // 524,288
    unsigned short* Xb = (unsigned short*)(base + 22812672 + 524288);    // 256*4224*2 = 2,162,688
    unsigned short* Yb = (unsigned short*)(base + 23336960 + 2162688);   // 2,162,688
    // Wlt/Zb alias the Sp region (consumed by k_lv_mfma before k_pgemm writes Sp)
    unsigned short* Wlt = (unsigned short*)Sp;                           // NP*KP*2 = 2,433,024
    unsigned short* Zb  = (unsigned short*)((char*)Sp + 2433024);        // 512*KP*2 = 1,081,344

    const size_t need = 23336960ull + 2162688ull + 2162688ull;           // 27,662,336 B
    const bool fast = (ws_size >= need);

    if (fast) {
        k_cvtboth<<<dim3(36, 33, 2), 256, 0, stream>>>(Wfe, Wlv, Wt, Wlt);
        k_fe_mfma<<<dim3(4, 128), 256, 0, stream>>>(tri, tei, Wt, bfe, Z, Zb);
        k_tgt    <<<2, 256, 0, stream>>>(trt, tet, Z, Zb, Hs_te, cterm);
        k_lv_mfma<<<dim3(9, 4, KSPLIT), 256, 0, stream>>>(Zb, Wlt, Cacc);
        k_lv_ep  <<<dim3(33, 16), 256, 0, stream>>>(Cacc, Z, blv, Xb, Yb, Hs_te, cterm);
        k_pgemm  <<<dim3(2, 2, 16), 256, 0, stream>>>(Xb, Yb, Sp);
        k_soft   <<<256, 256, 0, stream>>>(Sp, Hs_te, cterm, outp);
    } else {
        // fallback fp32 path, old layout
        float* Zf    = (float*)d_ws;
        float* E_tr  = Zf + (size_t)512 * TDIM;
        float* R_tr  = E_tr + (size_t)256 * TDIM;
        float* muT   = R_tr + (size_t)256 * TDIM;
        float* E_teT = muT + (size_t)TDIM * 256;
        float* R_teT = E_teT + (size_t)TDIM * 256;
        float* Hs    = R_teT + (size_t)TDIM * 256;
        float* Spf   = Hs + 256;
        k_fe_f32 <<<dim3(4, 128), 256, 0, stream>>>(tri, tei, Wfe, bfe, Zf, muT);
        k_tgt_f32<<<2, 256, 0, stream>>>(trt, tet, Zf, muT, Hs);
        k_lv     <<<dim3(17, 8), 256, 0, stream>>>(Zf, Wlv, blv, E_tr, R_tr, E_teT, R_teT, Hs);
        k_pair   <<<dim3(32, 16), 256, 0, stream>>>(Zf, E_tr, R_tr, muT, E_teT, R_teT, Spf);
        k_soft_fb<<<256, 256, 0, stream>>>(Spf, Hs, outp);
    }
}

// Round 7
// 143.980 us; speedup vs baseline: 1.2118x; 1.0944x over previous
//
#include <hip/hip_runtime.h>
#include <math.h>

#define TDIM 1026
#define KP 1056          // K padded for LV GEMM (33 * 32)
#define NP 1152          // N padded for LV GEMM (9 * 128)
#define KSPLIT 7
#define KK 4224          // pairwise GEMM K: 4 components x 1056

typedef __attribute__((ext_vector_type(8))) short bf16x8;
typedef __attribute__((ext_vector_type(4))) float f32x4;

// ---- fp32 -> bf16 RNE helpers ------------------------------------------------
__device__ inline unsigned int pk_bf16(float a, float b) {
    unsigned int ua = __float_as_uint(a), ub = __float_as_uint(b);
    ua = (ua + 0x7FFFu + ((ua >> 16) & 1u)) >> 16;
    ub = (ub + 0x7FFFu + ((ub >> 16) & 1u)) & 0xFFFF0000u;
    return ua | ub;
}
__device__ inline unsigned short f2bf(float a) {
    unsigned int ua = __float_as_uint(a);
    return (unsigned short)((ua + 0x7FFFu + ((ua >> 16) & 1u)) >> 16);
}

// ---- convert + transpose both weight matrices to bf16 [n][k] -----------------
__global__ __launch_bounds__(256)
void k_cvtboth(const float* __restrict__ Wfe, const float* __restrict__ Wlv,
               unsigned short* __restrict__ Wt, unsigned short* __restrict__ Wlt)
{
    __shared__ float T[32][33];
    const int z = blockIdx.z;
    if (z && (blockIdx.x >= 16 || blockIdx.y >= 16)) return;
    const float* W = z ? Wfe : Wlv;
    unsigned short* D = z ? Wt : Wlt;
    const int S  = z ? 512 : TDIM;
    const int DS = z ? 512 : KP;
    const int n0 = blockIdx.x * 32, k0 = blockIdx.y * 32;
    const int t = threadIdx.x;
    {
        int ky = t >> 3, nx = (t & 7) * 4;
#pragma unroll
        for (int i = 0; i < 4; ++i) {
            float v = 0.f;
            if (k0 + ky < S && n0 + nx + i < S)
                v = W[(size_t)(k0 + ky) * S + n0 + nx + i];
            T[nx + i][ky] = v;
        }
    }
    __syncthreads();
    {
        int ny = t >> 3, kx = (t & 7) * 4;
        ushort4 o;
        o.x = f2bf(T[ny][kx + 0]); o.y = f2bf(T[ny][kx + 1]);
        o.z = f2bf(T[ny][kx + 2]); o.w = f2bf(T[ny][kx + 3]);
        *(ushort4*)(D + (size_t)(n0 + ny) * DS + k0 + kx) = o;
    }
}

// ---- Kernel 1: bf16 MFMA FE GEMM (fused fp32->bf16 A), 64x128 tiles ----------
// Grid (256 row-tiles, 4 col-tiles): the 4 col-tiles sharing A rows have linear
// block IDs differing by 256 (=0 mod 8) -> same XCD -> one L2 fetch of A serves
// all four. 1024 blocks = 4 blocks/CU for latency hiding.
__global__ __launch_bounds__(256)
void k_fe_mfma(const float* __restrict__ Atr, const float* __restrict__ Ate,
               const unsigned short* __restrict__ Wt,
               const float* __restrict__ bfe, float* __restrict__ Z,
               unsigned short* __restrict__ Zb)
{
    __shared__ unsigned short As[64 * 40];
    __shared__ unsigned short Bs[128 * 40];
    __shared__ float2 sbuf[2 * 128];

    const int tid  = threadIdx.x;
    const int lane = tid & 63;
    const int wave = tid >> 6;           // wave covers 64 rows x 32 cols
    const int m = lane & 15, quad = lane >> 4;
    const int row0 = blockIdx.x * 64;
    const int col0 = blockIdx.y * 128;
    const float* A = (row0 < 8192) ? Atr : Ate;
    const int ar0 = row0 & 8191;

    f32x4 acc[4][2];
#pragma unroll
    for (int i = 0; i < 4; ++i)
#pragma unroll
        for (int j = 0; j < 2; ++j) acc[i][j] = (f32x4){0.f, 0.f, 0.f, 0.f};

    const int srA = tid >> 2, skA = tid & 3;   // A: row, k-octet (8 elems)
    const int srB = tid >> 1, skB = tid & 1;   // B: row, k-half (16 elems)

    float4 pa0, pa1;     // prefetched A (fp32, 8 elems)
    uint4  pb0, pb1;     // prefetched B (bf16, 16 elems)

#define FE_PRELOAD(K0)                                                          \
    {                                                                           \
        const float* ap = A + (size_t)(ar0 + srA) * 512 + (K0) + skA * 8;       \
        pa0 = *(const float4*)(ap);                                             \
        pa1 = *(const float4*)(ap + 4);                                         \
        const unsigned short* bp = Wt + (size_t)(col0 + srB) * 512 + (K0) + skB * 16; \
        pb0 = *(const uint4*)(bp);                                              \
        pb1 = *(const uint4*)(bp + 8);                                          \
    }

    FE_PRELOAD(0)
    for (int k0 = 0; k0 < 512; k0 += 32) {
        __syncthreads();
        {
            uint4 va;
            va.x = pk_bf16(pa0.x, pa0.y); va.y = pk_bf16(pa0.z, pa0.w);
            va.z = pk_bf16(pa1.x, pa1.y); va.w = pk_bf16(pa1.z, pa1.w);
            *(uint4*)(As + srA * 40 + skA * 8) = va;
            *(uint4*)(Bs + srB * 40 + skB * 16)     = pb0;
            *(uint4*)(Bs + srB * 40 + skB * 16 + 8) = pb1;
        }
        __syncthreads();
        if (k0 + 32 < 512) FE_PRELOAD(k0 + 32)   // overlaps ds_read + MFMA
        bf16x8 af[4], bfr[2];
#pragma unroll
        for (int ti = 0; ti < 4; ++ti)
            af[ti] = *(const bf16x8*)(As + (ti * 16 + m) * 40 + quad * 8);
#pragma unroll
        for (int tj = 0; tj < 2; ++tj)
            bfr[tj] = *(const bf16x8*)(Bs + (wave * 32 + tj * 16 + m) * 40 + quad * 8);
#pragma unroll
        for (int ti = 0; ti < 4; ++ti)
#pragma unroll
            for (int tj = 0; tj < 2; ++tj)
                acc[ti][tj] = __builtin_amdgcn_mfma_f32_16x16x32_bf16(
                    af[ti], bfr[tj], acc[ti][tj], 0, 0, 0);
    }

    // epilogue: bias + relu, per-episode (32-row) column sums; 64 rows = 2 episodes
#pragma unroll
    for (int ep = 0; ep < 2; ++ep) {
#pragma unroll
        for (int tj = 0; tj < 2; ++tj) {
            int colL = wave * 32 + tj * 16 + m;
            float b = bfe[col0 + colL];
            float s1 = 0.f, s2 = 0.f;
#pragma unroll
            for (int p = 0; p < 2; ++p) {
                int ti = ep * 2 + p;
#pragma unroll
                for (int r = 0; r < 4; ++r) {
                    float v = fmaxf(acc[ti][tj][r] + b, 0.f);
                    s1 += v; s2 += v * v;
                }
            }
            s1 += __shfl_xor(s1, 16); s1 += __shfl_xor(s1, 32);
            s2 += __shfl_xor(s2, 16); s2 += __shfl_xor(s2, 32);
            if (lane < 16) sbuf[ep * 128 + colL] = make_float2(s1, s2);
        }
    }
    __syncthreads();
    {
        int ep = tid >> 7, cl = tid & 127;   // 256 threads = 2 eps x 128 cols
        float2 pr = sbuf[ep * 128 + cl];
        float mean = pr.x * (1.f / 32.f);
        float var  = (pr.y - 32.f * mean * mean) * (1.f / 31.f);   // ddof=1
        float sd   = sqrtf(fmaxf(var, 0.f));
        int e = blockIdx.x * 2 + ep;
        int f = col0 + cl;
        Z[(size_t)e * TDIM + 1 + f]   = mean;
        Z[(size_t)e * TDIM + 514 + f] = sd;
        Zb[(size_t)e * KP + 1 + f]    = f2bf(mean);
        Zb[(size_t)e * KP + 514 + f]  = f2bf(sd);
    }
}

// ---------------- Kernel 2: targets stats + Zb pad + Hs/cterm zero ------------
__global__ __launch_bounds__(256)
void k_tgt(const float* __restrict__ Ttr, const float* __restrict__ Tte,
           float* __restrict__ Z, unsigned short* __restrict__ Zb,
           float* __restrict__ Hs_te, float* __restrict__ cterm)
{
    if (blockIdx.x == 0) { Hs_te[threadIdx.x] = 0.f; cterm[threadIdx.x] = 0.f; }
    int e = blockIdx.x * 256 + threadIdx.x;
    if (e >= 512) return;
    const float* p = (e < 256) ? (Ttr + (size_t)e * 32) : (Tte + (size_t)(e - 256) * 32);
    float S1 = 0.f, S2 = 0.f;
#pragma unroll
    for (int n = 0; n < 32; ++n) { float v = p[n]; S1 += v; S2 += v * v; }
    float mean = S1 * (1.f / 32.f);
    float var  = (S2 - 32.f * mean * mean) * (1.f / 31.f);
    float sd   = sqrtf(fmaxf(var, 0.f));
    Z[(size_t)e * TDIM + 0]   = mean;
    Z[(size_t)e * TDIM + 513] = sd;
    Zb[(size_t)e * KP + 0]    = f2bf(mean);
    Zb[(size_t)e * KP + 513]  = f2bf(sd);
#pragma unroll
    for (int c = TDIM; c < KP; ++c) Zb[(size_t)e * KP + c] = 0;   // K pad
}

// ---- Kernel 3a: bf16 MFMA LV GEMM, split-K=7, raw fp32 partials --------------
__global__ __launch_bounds__(256)
void k_lv_mfma(const unsigned short* __restrict__ Zb,
               const unsigned short* __restrict__ Wlt,
               float* __restrict__ Cacc)
{
    __shared__ unsigned short As[128 * 40];
    __shared__ unsigned short Bs[128 * 40];

    const int tid  = threadIdx.x;
    const int lane = tid & 63;
    const int wave = tid >> 6;
    const int wr = wave >> 1, wc = wave & 1;
    const int m = lane & 15, quad = lane >> 4;
    const int col0 = blockIdx.x * 128;
    const int row0 = blockIdx.y * 128;
    const int p    = blockIdx.z;
    const int it0  = (p < 5) ? p * 5 : 25 + (p - 5) * 4;
    const int itn  = (p < 5) ? 5 : 4;

    f32x4 acc[4][4];
#pragma unroll
    for (int i = 0; i < 4; ++i)
#pragma unroll
        for (int j = 0; j < 4; ++j) acc[i][j] = (f32x4){0.f, 0.f, 0.f, 0.f};

    const int srow = tid >> 2;
    const int skc  = tid & 3;

    for (int it = it0; it < it0 + itn; ++it) {
        int k0 = it * 32;
#pragma unroll
        for (int s = 0; s < 2; ++s) {
            int row = srow + s * 64;
            uint4 va = *(const uint4*)(Zb  + (size_t)(row0 + row) * KP + k0 + skc * 8);
            uint4 vb = *(const uint4*)(Wlt + (size_t)(col0 + row) * KP + k0 + skc * 8);
            *(uint4*)(As + row * 40 + skc * 8) = va;
            *(uint4*)(Bs + row * 40 + skc * 8) = vb;
        }
        __syncthreads();
        bf16x8 af[4], bfr[4];
#pragma unroll
        for (int t2 = 0; t2 < 4; ++t2) {
            af[t2]  = *(const bf16x8*)(As + (wr * 64 + t2 * 16 + m) * 40 + quad * 8);
            bfr[t2] = *(const bf16x8*)(Bs + (wc * 64 + t2 * 16 + m) * 40 + quad * 8);
        }
#pragma unroll
        for (int ti = 0; ti < 4; ++ti)
#pragma unroll
            for (int tj = 0; tj < 4; ++tj)
                acc[ti][tj] = __builtin_amdgcn_mfma_f32_16x16x32_bf16(
                    af[ti], bfr[tj], acc[ti][tj], 0, 0, 0);
        __syncthreads();
    }

    float* C = Cacc + (size_t)p * 512 * NP;
#pragma unroll
    for (int ti = 0; ti < 4; ++ti)
#pragma unroll
        for (int tj = 0; tj < 4; ++tj) {
            int c = col0 + wc * 64 + tj * 16 + m;
#pragma unroll
            for (int r = 0; r < 4; ++r) {
                int rg = row0 + wr * 64 + ti * 16 + quad * 4 + r;
                C[(size_t)rg * NP + c] = acc[ti][tj][r];
            }
        }
}

// ---- Kernel 3b: reduce partials + bias/clip/exp; build pairwise-GEMM operands
__global__ __launch_bounds__(256)
void k_lv_ep(const float* __restrict__ Cacc, const float* __restrict__ Zf,
             const float* __restrict__ blv,
             unsigned short* __restrict__ Xb, unsigned short* __restrict__ Yb,
             float* __restrict__ Hs_te, float* __restrict__ cterm)
{
    const int t = threadIdx.x;
    const int rl = t >> 3;
    const int ci = t & 7;
    const int r  = blockIdx.y * 32 + rl;
    const int c0 = blockIdx.x * 32 + ci * 4;
    const bool is_te = (r >= 256);

    float4 s = make_float4(0.f, 0.f, 0.f, 0.f);
#pragma unroll
    for (int p = 0; p < KSPLIT; ++p) {
        float4 v = *(const float4*)(Cacc + (size_t)p * 512 * NP + (size_t)r * NP + c0);
        s.x += v.x; s.y += v.y; s.z += v.z; s.w += v.w;
    }
    float sv[4] = {s.x, s.y, s.z, s.w};

    unsigned short* O = is_te ? (Yb + (size_t)(r - 256) * KK) : (Xb + (size_t)r * KK);
    float h = 0.f, ct = 0.f;
#pragma unroll
    for (int q = 0; q < 4; ++q) {
        int c = c0 + q;
        bool cok = (c < TDIM);
        ushort4 o = make_ushort4(0, 0, 0, 0);
        if (cok) {
            float x = fminf(fmaxf(sv[q] + blv[c], -9.f), -2.f);
            float E = expf(x);
            float R = expf(-x);
            float mm = Zf[(size_t)r * TDIM + c];
            if (!is_te) {
                o.x = f2bf(E + mm * mm);
                o.y = f2bf(R);
                o.z = f2bf(-2.f * mm * R);
                o.w = f2bf(-2.f * mm);
            } else {
                o.x = f2bf(R);
                o.y = f2bf(E + mm * mm);
                o.z = f2bf(mm);
                o.w = f2bf(mm * R);
                h  += x;
                ct += mm * mm * R;
            }
        }
        *(ushort4*)(O + 4 * c) = o;
    }
    if (is_te) {
        h  += __shfl_xor(h, 1);  h  += __shfl_xor(h, 2);  h  += __shfl_xor(h, 4);
        ct += __shfl_xor(ct, 1); ct += __shfl_xor(ct, 2); ct += __shfl_xor(ct, 4);
        if (ci == 0) {
            atomicAdd(Hs_te + (r - 256), h);
            atomicAdd(cterm + (r - 256), ct);
        }
    }
}

// ---- Kernel 4: pairwise GEMM S = X * Y^T, 256x256xKK bf16, split-K=16 --------
__global__ __launch_bounds__(256)
void k_pgemm(const unsigned short* __restrict__ Xb,
             const unsigned short* __restrict__ Yb,
             float* __restrict__ Sp)
{
    __shared__ unsigned short As[128 * 40];
    __shared__ unsigned short Bs[128 * 40];

    const int tid  = threadIdx.x;
    const int lane = tid & 63;
    const int wave = tid >> 6;
    const int wr = wave >> 1, wc = wave & 1;
    const int m = lane & 15, quad = lane >> 4;
    const int col0 = blockIdx.x * 128;
    const int row0 = blockIdx.y * 128;
    const int p    = blockIdx.z;           // 0..15; 132 iters = 4*9 + 12*8
    const int it0  = (p < 4) ? p * 9 : 36 + (p - 4) * 8;
    const int itn  = (p < 4) ? 9 : 8;

    f32x4 acc[4][4];
#pragma unroll
    for (int i = 0; i < 4; ++i)
#pragma unroll
        for (int j = 0; j < 4; ++j) acc[i][j] = (f32x4){0.f, 0.f, 0.f, 0.f};

    const int srow = tid >> 2;
    const int skc  = tid & 3;

    for (int it = it0; it < it0 + itn; ++it) {
        int k0 = it * 32;
#pragma unroll
        for (int s = 0; s < 2; ++s) {
            int row = srow + s * 64;
            uint4 va = *(const uint4*)(Xb + (size_t)(row0 + row) * KK + k0 + skc * 8);
            uint4 vb = *(const uint4*)(Yb + (size_t)(col0 + row) * KK + k0 + skc * 8);
            *(uint4*)(As + row * 40 + skc * 8) = va;
            *(uint4*)(Bs + row * 40 + skc * 8) = vb;
        }
        __syncthreads();
        bf16x8 af[4], bfr[4];
#pragma unroll
        for (int t2 = 0; t2 < 4; ++t2) {
            af[t2]  = *(const bf16x8*)(As + (wr * 64 + t2 * 16 + m) * 40 + quad * 8);
            bfr[t2] = *(const bf16x8*)(Bs + (wc * 64 + t2 * 16 + m) * 40 + quad * 8);
        }
#pragma unroll
        for (int ti = 0; ti < 4; ++ti)
#pragma unroll
            for (int tj = 0; tj < 4; ++tj)
                acc[ti][tj] = __builtin_amdgcn_mfma_f32_16x16x32_bf16(
                    af[ti], bfr[tj], acc[ti][tj], 0, 0, 0);
        __syncthreads();
    }

    float* C = Sp + (size_t)p * 65536;
#pragma unroll
    for (int ti = 0; ti < 4; ++ti)
#pragma unroll
        for (int tj = 0; tj < 4; ++tj) {
            int c = col0 + wc * 64 + tj * 16 + m;
#pragma unroll
            for (int r = 0; r < 4; ++r) {
                int rg = row0 + wr * 64 + ti * 16 + quad * 4 + r;
                C[(size_t)rg * 256 + c] = acc[ti][tj][r];
            }
        }
}

// ---- Kernel 5: row log_softmax + classes -------------------------------------
__global__ __launch_bounds__(256)
void k_soft(const float* __restrict__ Sp, const float* __restrict__ Hs_te,
            const float* __restrict__ cterm, float* __restrict__ outp)
{
    __shared__ float red[4], red2[4];
    const int i = blockIdx.x, j = threadIdx.x;
    float s = 0.f;
#pragma unroll
    for (int tc = 0; tc < 16; ++tc)
        s += Sp[((size_t)tc * 256 + i) * 256 + j];
    float v = -(0.5f * (s + cterm[j]) + Hs_te[j]);

    float m = v;
#pragma unroll
    for (int o = 32; o > 0; o >>= 1) m = fmaxf(m, __shfl_xor(m, o));
    if ((j & 63) == 0) red[j >> 6] = m;
    __syncthreads();
    m = fmaxf(fmaxf(red[0], red[1]), fmaxf(red[2], red[3]));

    float p = v - m;
    float t = expf(p);
#pragma unroll
    for (int o = 32; o > 0; o >>= 1) t += __shfl_xor(t, o);
    if ((j & 63) == 0) red2[j >> 6] = t;
    __syncthreads();
    t = red2[0] + red2[1] + red2[2] + red2[3];

    outp[(size_t)i * 256 + j] = p - logf(t);
    if (i == 0) outp[65536 + j] = (float)j;
}

// =================== Fallback fp32 path (ws too small) ========================
__global__ __launch_bounds__(256)
void k_fe_f32(const float* __restrict__ Atr, const float* __restrict__ Ate,
              const float* __restrict__ Wfe, const float* __restrict__ bfe,
              float* __restrict__ Z, float* __restrict__ muT_te)
{
    __shared__ float lds[4224];
    float* Ast = lds;
    float* Bs  = lds + 2112;
    const int tid = threadIdx.x;
    const int tx = tid & 15;
    const int ty = tid >> 4;
    const int col0 = blockIdx.x * 128;
    const int row0 = blockIdx.y * 128;
    const float* A = (row0 < 8192) ? Atr : Ate;
    const int ar0 = (row0 < 8192) ? row0 : (row0 - 8192);

    float acc[8][8];
#pragma unroll
    for (int i = 0; i < 8; ++i)
#pragma unroll
        for (int j = 0; j < 8; ++j) acc[i][j] = 0.f;

    for (int k0 = 0; k0 < 512; k0 += 16) {
#pragma unroll
        for (int s = 0; s < 2; ++s) {
            int u = tid + s * 256;
            int row = u >> 2, q = u & 3;
            float4 v = *(const float4*)(A + (size_t)(ar0 + row) * 512 + k0 + q * 4);
            Ast[(q * 4 + 0) * 132 + row] = v.x;
            Ast[(q * 4 + 1) * 132 + row] = v.y;
            Ast[(q * 4 + 2) * 132 + row] = v.z;
            Ast[(q * 4 + 3) * 132 + row] = v.w;
        }
#pragma unroll
        for (int s = 0; s < 2; ++s) {
            int u = tid + s * 256;
            int kk = u >> 5, c8 = u & 31;
            float4 v = *(const float4*)(Wfe + (size_t)(k0 + kk) * 512 + col0 + c8 * 4);
            *(float4*)(Bs + kk * 132 + c8 * 4) = v;
        }
        __syncthreads();
#pragma unroll
        for (int kk = 0; kk < 16; ++kk) {
            float4 a0 = *(const float4*)(Ast + kk * 132 + ty * 8);
            float4 a1 = *(const float4*)(Ast + kk * 132 + ty * 8 + 4);
            float4 b0 = *(const float4*)(Bs + kk * 132 + tx * 4);
            float4 b1 = *(const float4*)(Bs + kk * 132 + 64 + tx * 4);
            float av[8] = {a0.x, a0.y, a0.z, a0.w, a1.x, a1.y, a1.z, a1.w};
            float bv[8] = {b0.x, b0.y, b0.z, b0.w, b1.x, b1.y, b1.z, b1.w};
#pragma unroll
            for (int i = 0; i < 8; ++i)
#pragma unroll
                for (int j = 0; j < 8; ++j)
                    acc[i][j] = fmaf(av[i], bv[j], acc[i][j]);
        }
        __syncthreads();
    }

    float2* sbuf = (float2*)lds;
#pragma unroll
    for (int j = 0; j < 8; ++j) {
        int cl = (j < 4) ? (tx * 4 + j) : (64 + tx * 4 + (j - 4));
        float b = bfe[col0 + cl];
        float s1 = 0.f, s2 = 0.f;
#pragma unroll
        for (int i = 0; i < 8; ++i) {
            float v = acc[i][j] + b;
            v = fmaxf(v, 0.f);
            s1 += v; s2 += v * v;
        }
        sbuf[ty * 128 + cl] = make_float2(s1, s2);
    }
    __syncthreads();
    for (int idx = tid; idx < 512; idx += 256) {
        int ep = idx >> 7, cl = idx & 127;
        float S1 = 0.f, S2 = 0.f;
#pragma unroll
        for (int q = 0; q < 4; ++q) {
            float2 p = sbuf[(ep * 4 + q) * 128 + cl];
            S1 += p.x; S2 += p.y;
        }
        float mean = S1 * (1.f / 32.f);
        float var  = (S2 - 32.f * mean * mean) * (1.f / 31.f);
        float sd   = sqrtf(fmaxf(var, 0.f));
        int e = (row0 >> 5) + ep;
        int f = col0 + cl;
        Z[(size_t)e * TDIM + 1 + f]   = mean;
        Z[(size_t)e * TDIM + 514 + f] = sd;
        if (e >= 256) {
            int j2 = e - 256;
            muT_te[(size_t)(1 + f) * 256 + j2]   = mean;
            muT_te[(size_t)(514 + f) * 256 + j2] = sd;
        }
    }
}

__global__ __launch_bounds__(256)
void k_tgt_f32(const float* __restrict__ Ttr, const float* __restrict__ Tte,
               float* __restrict__ Z, float* __restrict__ muT_te,
               float* __restrict__ Hs_te)
{
    if (blockIdx.x == 0) Hs_te[threadIdx.x] = 0.f;
    int e = blockIdx.x * 256 + threadIdx.x;
    if (e >= 512) return;
    const float* p = (e < 256) ? (Ttr + (size_t)e * 32) : (Tte + (size_t)(e - 256) * 32);
    float S1 = 0.f, S2 = 0.f;
#pragma unroll
    for (int n = 0; n < 32; ++n) { float v = p[n]; S1 += v; S2 += v * v; }
    float mean = S1 * (1.f / 32.f);
    float var  = (S2 - 32.f * mean * mean) * (1.f / 31.f);
    float sd   = sqrtf(fmaxf(var, 0.f));
    Z[(size_t)e * TDIM + 0]   = mean;
    Z[(size_t)e * TDIM + 513] = sd;
    if (e >= 256) {
        muT_te[(size_t)0 * 256 + (e - 256)]   = mean;
        muT_te[(size_t)513 * 256 + (e - 256)] = sd;
    }
}

__global__ __launch_bounds__(256)
void k_lv(const float* __restrict__ Z, const float* __restrict__ Wlv,
          const float* __restrict__ blv,
          float* __restrict__ E_tr, float* __restrict__ R_tr,
          float* __restrict__ E_teT, float* __restrict__ R_teT,
          float* __restrict__ Hs_te)
{
    __shared__ float Ast[16 * 68];
    __shared__ float Bs[16 * 68];
    const int tid = threadIdx.x;
    const int tx = tid & 15;
    const int ty = tid >> 4;
    const int col0 = blockIdx.x * 64;
    const int row0 = blockIdx.y * 64;

    float acc[4][4];
#pragma unroll
    for (int i = 0; i < 4; ++i)
#pragma unroll
        for (int j = 0; j < 4; ++j) acc[i][j] = 0.f;

    for (int k0 = 0; k0 < TDIM; k0 += 16) {
        {
            int row = tid >> 2, kp = tid & 3;
            const float* src = Z + (size_t)(row0 + row) * TDIM + k0 + kp * 4;
            float x0 = 0.f, x1 = 0.f, x2 = 0.f, x3 = 0.f;
            if (k0 + kp * 4 + 1 < TDIM) { float2 v = *(const float2*)(src);     x0 = v.x; x1 = v.y; }
            if (k0 + kp * 4 + 3 < TDIM) { float2 v = *(const float2*)(src + 2); x2 = v.x; x3 = v.y; }
            Ast[(kp * 4 + 0) * 68 + row] = x0;
            Ast[(kp * 4 + 1) * 68 + row] = x1;
            Ast[(kp * 4 + 2) * 68 + row] = x2;
            Ast[(kp * 4 + 3) * 68 + row] = x3;
        }
        {
            int kk = tid >> 4, cg = tid & 15;
#pragma unroll
            for (int c = 0; c < 4; ++c) {
                int col = col0 + cg * 4 + c;
                float v = 0.f;
                if (k0 + kk < TDIM && col < TDIM)
                    v = Wlv[(size_t)(k0 + kk) * TDIM + col];
                Bs[kk * 68 + cg * 4 + c] = v;
            }
        }
        __syncthreads();
#pragma unroll
        for (int kk = 0; kk < 16; ++kk) {
            float4 a = *(const float4*)(Ast + kk * 68 + ty * 4);
            float4 b = *(const float4*)(Bs + kk * 68 + tx * 4);
            float av[4] = {a.x, a.y, a.z, a.w};
            float bv[4] = {b.x, b.y, b.z, b.w};
#pragma unroll
            for (int i = 0; i < 4; ++i)
#pragma unroll
                for (int j = 0; j < 4; ++j)
                    acc[i][j] = fmaf(av[i], bv[j], acc[i][j]);
        }
        __syncthreads();
    }

    float hpart[4] = {0.f, 0.f, 0.f, 0.f};
#pragma unroll
    for (int i = 0; i < 4; ++i) {
        int r = row0 + ty * 4 + i;
#pragma unroll
        for (int j = 0; j < 4; ++j) {
            int c = col0 + tx * 4 + j;
            if (c < TDIM) {
                float lv = acc[i][j] + blv[c];
                lv = fminf(fmaxf(lv, -9.f), -2.f);
                float E = expf(lv);
                float R = expf(-lv);
                if (r < 256) {
                    E_tr[(size_t)r * TDIM + c] = E;
                    R_tr[(size_t)r * TDIM + c] = R;
                } else {
                    E_teT[(size_t)c * 256 + (r - 256)] = E;
                    R_teT[(size_t)c * 256 + (r - 256)] = R;
                    hpart[i] += lv;
                }
            }
        }
    }
    if (row0 >= 256) {
        __syncthreads();
        float* hbuf = Ast;
#pragma unroll
        for (int i = 0; i < 4; ++i) hbuf[(ty * 4 + i) * 16 + tx] = hpart[i];
        __syncthreads();
        if (tid < 64) {
            float s = 0.f;
#pragma unroll
            for (int x = 0; x < 16; ++x) s += hbuf[tid * 16 + x];
            atomicAdd(Hs_te + (row0 - 256 + tid), s);
        }
    }
}

#define TCH 65
__global__ __launch_bounds__(256)
void k_pair(const float* __restrict__ Z, const float* __restrict__ E_tr,
            const float* __restrict__ R_tr, const float* __restrict__ muT_te,
            const float* __restrict__ E_teT, const float* __restrict__ R_teT,
            float* __restrict__ Sp)
{
    __shared__ float Lm[8 * 68], Le[8 * 68], Lr[8 * 68];
    const int tid = threadIdx.x;
    const int i0 = blockIdx.x * 8;
    const int t0 = blockIdx.y * TCH;
    const int tlen = min(TCH, TDIM - t0);

    if (tid < tlen) {
#pragma unroll
        for (int r = 0; r < 8; ++r) {
            size_t off = (size_t)(i0 + r) * TDIM + t0 + tid;
            Lm[r * 68 + tid] = Z[off];
            Le[r * 68 + tid] = E_tr[off];
            Lr[r * 68 + tid] = R_tr[off];
        }
    }
    __syncthreads();

    float S[8];
#pragma unroll
    for (int r = 0; r < 8; ++r) S[r] = 0.f;
    const int j = tid;
    for (int tt = 0; tt < tlen; ++tt) {
        size_t o = (size_t)(t0 + tt) * 256 + j;
        float m2 = muT_te[o], e2 = E_teT[o], r2 = R_teT[o];
#pragma unroll
        for (int r = 0; r < 8; ++r) {
            float m1 = Lm[r * 68 + tt];
            float e1 = Le[r * 68 + tt];
            float r1 = Lr[r * 68 + tt];
            float d = m1 - m2;
            S[r] += e1 * r2 + e2 * r1 + d * d * (r1 + r2);
        }
    }
#pragma unroll
    for (int r = 0; r < 8; ++r)
        Sp[((size_t)blockIdx.y * 256 + i0 + r) * 256 + j] = S[r];
}

__global__ __launch_bounds__(256)
void k_soft_fb(const float* __restrict__ Sp, const float* __restrict__ Hs_te,
               float* __restrict__ outp)
{
    __shared__ float red[4], red2[4];
    const int i = blockIdx.x, j = threadIdx.x;
    float s = 0.f;
#pragma unroll
    for (int tc = 0; tc < 16; ++tc)
        s += Sp[((size_t)tc * 256 + i) * 256 + j];
    float v = -(0.5f * s + Hs_te[j]);

    float m = v;
#pragma unroll
    for (int o = 32; o > 0; o >>= 1) m = fmaxf(m, __shfl_xor(m, o));
    if ((j & 63) == 0) red[j >> 6] = m;
    __syncthreads();
    m = fmaxf(fmaxf(red[0], red[1]), fmaxf(red[2], red[3]));

    float p = v - m;
    float t = expf(p);
#pragma unroll
    for (int o = 32; o > 0; o >>= 1) t += __shfl_xor(t, o);
    if ((j & 63) == 0) red2[j >> 6] = t;
    __syncthreads();
    t = red2[0] + red2[1] + red2[2] + red2[3];

    outp[(size_t)i * 256 + j] = p - logf(t);
    if (i == 0) outp[65536 + j] = (float)j;
}

extern "C" void kernel_launch(void* const* d_in, const int* in_sizes, int n_in,
                              void* d_out, int out_size, void* d_ws, size_t ws_size,
                              hipStream_t stream)
{
    const float* tri = (const float*)d_in[0];
    const float* trt = (const float*)d_in[1];
    const float* tei = (const float*)d_in[2];
    const float* tet = (const float*)d_in[3];
    const float* Wfe = (const float*)d_in[4];
    const float* bfe = (const float*)d_in[5];
    const float* Wlv = (const float*)d_in[6];
    const float* blv = (const float*)d_in[7];
    float* outp = (float*)d_out;

    // ---- fast-path layout ----
    char* base = (char*)d_ws;
    float* Z     = (float*)base;                                   // 512*1026*4 = 2,101,248
    float* Sp    = (float*)(base + 2101248);                       // 16*256*256*4 = 4,194,304
    float* Hs_te = (float*)(base + 2101248 + 4194304);             // 1024
    float* cterm = (float*)(base + 2101248 + 4194304 + 1024);      // 1024
    float* Cacc  = (float*)(base + 6296576 + 1024);                // 7*512*1152*4 = 16,515,072
    unsigned short* Wt = (unsigned short*)(base + 6297600 + 16515072);   // 524,288
    unsigned short* Xb = (unsigned short*)(base + 22812672 + 524288);    // 256*4224*2 = 2,162,688
    unsigned short* Yb = (unsigned short*)(base + 23336960 + 2162688);   // 2,162,688
    // Wlt/Zb alias the Sp region (consumed by k_lv_mfma before k_pgemm writes Sp)
    unsigned short* Wlt = (unsigned short*)Sp;                           // NP*KP*2 = 2,433,024
    unsigned short* Zb  = (unsigned short*)((char*)Sp + 2433024);        // 512*KP*2 = 1,081,344

    const size_t need = 23336960ull + 2162688ull + 2162688ull;           // 27,662,336 B
    const bool fast = (ws_size >= need);

    if (fast) {
        k_cvtboth<<<dim3(36, 33, 2), 256, 0, stream>>>(Wfe, Wlv, Wt, Wlt);
        k_fe_mfma<<<dim3(256, 4), 256, 0, stream>>>(tri, tei, Wt, bfe, Z, Zb);
        k_tgt    <<<2, 256, 0, stream>>>(trt, tet, Z, Zb, Hs_te, cterm);
        k_lv_mfma<<<dim3(9, 4, KSPLIT), 256, 0, stream>>>(Zb, Wlt, Cacc);
        k_lv_ep  <<<dim3(33, 16), 256, 0, stream>>>(Cacc, Z, blv, Xb, Yb, Hs_te, cterm);
        k_pgemm  <<<dim3(2, 2, 16), 256, 0, stream>>>(Xb, Yb, Sp);
        k_soft   <<<256, 256, 0, stream>>>(Sp, Hs_te, cterm, outp);
    } else {
        // fallback fp32 path, old layout
        float* Zf    = (float*)d_ws;
        float* E_tr  = Zf + (size_t)512 * TDIM;
        float* R_tr  = E_tr + (size_t)256 * TDIM;
        float* muT   = R_tr + (size_t)256 * TDIM;
        float* E_teT = muT + (size_t)TDIM * 256;
        float* R_teT = E_teT + (size_t)TDIM * 256;
        float* Hs    = R_teT + (size_t)TDIM * 256;
        float* Spf   = Hs + 256;
        k_fe_f32 <<<dim3(4, 128), 256, 0, stream>>>(tri, tei, Wfe, bfe, Zf, muT);
        k_tgt_f32<<<2, 256, 0, stream>>>(trt, tet, Zf, muT, Hs);
        k_lv     <<<dim3(17, 8), 256, 0, stream>>>(Zf, Wlv, blv, E_tr, R_tr, E_teT, R_teT, Hs);
        k_pair   <<<dim3(32, 16), 256, 0, stream>>>(Zf, E_tr, R_tr, muT, E_teT, R_teT, Spf);
        k_soft_fb<<<256, 256, 0, stream>>>(Spf, Hs, outp);
    }
}

// Round 8
// 139.273 us; speedup vs baseline: 1.2527x; 1.0338x over previous
//
#include <hip/hip_runtime.h>
#include <math.h>

#define TDIM 1026
#define KP 1056          // K padded for LV GEMM (33 * 32)
#define NP 1152          // N padded for LV GEMM (9 * 128)
#define KSPLIT 7
#define KK 4224          // pairwise GEMM K: 4 components x 1056

typedef __attribute__((ext_vector_type(8))) short bf16x8;
typedef __attribute__((ext_vector_type(4))) float f32x4;

// ---- fp32 -> bf16 RNE helpers ------------------------------------------------
__device__ inline unsigned int pk_bf16(float a, float b) {
    unsigned int ua = __float_as_uint(a), ub = __float_as_uint(b);
    ua = (ua + 0x7FFFu + ((ua >> 16) & 1u)) >> 16;
    ub = (ub + 0x7FFFu + ((ub >> 16) & 1u)) & 0xFFFF0000u;
    return ua | ub;
}
__device__ inline unsigned short f2bf(float a) {
    unsigned int ua = __float_as_uint(a);
    return (unsigned short)((ua + 0x7FFFu + ((ua >> 16) & 1u)) >> 16);
}

// ---- convert+transpose weights (z=0: W_lv, z=1: W_fe) + z=2: target stats ----
__global__ __launch_bounds__(256)
void k_cvtboth(const float* __restrict__ Wfe, const float* __restrict__ Wlv,
               unsigned short* __restrict__ Wt, unsigned short* __restrict__ Wlt,
               const float* __restrict__ Ttr, const float* __restrict__ Tte,
               float* __restrict__ Z, unsigned short* __restrict__ Zb,
               float* __restrict__ Hs_te, float* __restrict__ cterm)
{
    __shared__ float T[32][33];
    const int z = blockIdx.z;
    const int t = threadIdx.x;
    if (z == 2) {
        // target column stats (x col 0) + Zb K-pad zero + Hs/cterm zero
        if (blockIdx.y != 0 || blockIdx.x >= 2) return;
        if (blockIdx.x == 0) { Hs_te[t] = 0.f; cterm[t] = 0.f; }
        int e = blockIdx.x * 256 + t;
        const float* p = (e < 256) ? (Ttr + (size_t)e * 32) : (Tte + (size_t)(e - 256) * 32);
        float S1 = 0.f, S2 = 0.f;
#pragma unroll
        for (int n = 0; n < 32; ++n) { float v = p[n]; S1 += v; S2 += v * v; }
        float mean = S1 * (1.f / 32.f);
        float var  = (S2 - 32.f * mean * mean) * (1.f / 31.f);
        float sd   = sqrtf(fmaxf(var, 0.f));
        Z[(size_t)e * TDIM + 0]   = mean;
        Z[(size_t)e * TDIM + 513] = sd;
        Zb[(size_t)e * KP + 0]    = f2bf(mean);
        Zb[(size_t)e * KP + 513]  = f2bf(sd);
#pragma unroll
        for (int c = TDIM; c < KP; ++c) Zb[(size_t)e * KP + c] = 0;   // K pad
        return;
    }
    if (z && (blockIdx.x >= 16 || blockIdx.y >= 16)) return;
    const float* W = z ? Wfe : Wlv;
    unsigned short* D = z ? Wt : Wlt;
    const int S  = z ? 512 : TDIM;
    const int DS = z ? 512 : KP;
    const int n0 = blockIdx.x * 32, k0 = blockIdx.y * 32;
    {
        int ky = t >> 3, nx = (t & 7) * 4;
#pragma unroll
        for (int i = 0; i < 4; ++i) {
            float v = 0.f;
            if (k0 + ky < S && n0 + nx + i < S)
                v = W[(size_t)(k0 + ky) * S + n0 + nx + i];
            T[nx + i][ky] = v;
        }
    }
    __syncthreads();
    {
        int ny = t >> 3, kx = (t & 7) * 4;
        ushort4 o;
        o.x = f2bf(T[ny][kx + 0]); o.y = f2bf(T[ny][kx + 1]);
        o.z = f2bf(T[ny][kx + 2]); o.w = f2bf(T[ny][kx + 3]);
        *(ushort4*)(D + (size_t)(n0 + ny) * DS + k0 + kx) = o;
    }
}

// ---- Kernel 1: bf16 MFMA FE GEMM, 64x128 tiles, double-buffered LDS ----------
// Grid (256 row-tiles, 4 col-tiles): col-tiles sharing A rows land on the same
// XCD (linear IDs differ by 256 = 0 mod 8). One barrier per K-iter: write-first
// into buf[1-cur] (prefetched k+32), preload k+64, read+MFMA from buf[cur].
__global__ __launch_bounds__(256)
void k_fe_mfma(const float* __restrict__ Atr, const float* __restrict__ Ate,
               const unsigned short* __restrict__ Wt,
               const float* __restrict__ bfe, float* __restrict__ Z,
               unsigned short* __restrict__ Zb)
{
    __shared__ unsigned short As[2][64 * 40];
    __shared__ unsigned short Bs[2][128 * 40];
    __shared__ float2 sbuf[2 * 128];

    const int tid  = threadIdx.x;
    const int lane = tid & 63;
    const int wave = tid >> 6;           // wave covers 64 rows x 32 cols
    const int m = lane & 15, quad = lane >> 4;
    const int row0 = blockIdx.x * 64;
    const int col0 = blockIdx.y * 128;
    const float* A = (row0 < 8192) ? Atr : Ate;
    const int ar0 = row0 & 8191;

    f32x4 acc[4][2];
#pragma unroll
    for (int i = 0; i < 4; ++i)
#pragma unroll
        for (int j = 0; j < 2; ++j) acc[i][j] = (f32x4){0.f, 0.f, 0.f, 0.f};

    const int srA = tid >> 2, skA = tid & 3;   // A: row, k-octet (8 elems)
    const int srB = tid >> 1, skB = tid & 1;   // B: row, k-half (16 elems)

    float4 pa0, pa1;     // prefetched A (fp32, 8 elems)
    uint4  pb0, pb1;     // prefetched B (bf16, 16 elems)

#define FE_PRELOAD(K0)                                                          \
    {                                                                           \
        const float* ap = A + (size_t)(ar0 + srA) * 512 + (K0) + skA * 8;       \
        pa0 = *(const float4*)(ap);                                             \
        pa1 = *(const float4*)(ap + 4);                                         \
        const unsigned short* bp = Wt + (size_t)(col0 + srB) * 512 + (K0) + skB * 16; \
        pb0 = *(const uint4*)(bp);                                              \
        pb1 = *(const uint4*)(bp + 8);                                          \
    }
#define FE_WRITE(BUF)                                                           \
    {                                                                           \
        uint4 va;                                                               \
        va.x = pk_bf16(pa0.x, pa0.y); va.y = pk_bf16(pa0.z, pa0.w);             \
        va.z = pk_bf16(pa1.x, pa1.y); va.w = pk_bf16(pa1.z, pa1.w);             \
        *(uint4*)(As[BUF] + srA * 40 + skA * 8) = va;                           \
        *(uint4*)(Bs[BUF] + srB * 40 + skB * 16)     = pb0;                     \
        *(uint4*)(Bs[BUF] + srB * 40 + skB * 16 + 8) = pb1;                     \
    }

    FE_PRELOAD(0)
    FE_WRITE(0)
    FE_PRELOAD(32)
    __syncthreads();

    int cur = 0;
    for (int k0 = 0; k0 < 512; k0 += 32) {
        if (k0 + 32 < 512) {
            FE_WRITE(cur ^ 1)                 // stage prefetched k0+32 (safe: buf read-done at iter k0-32)
            if (k0 + 64 < 512) FE_PRELOAD(k0 + 64)   // full-iteration latency window
        }
        bf16x8 af[4], bfr[2];
#pragma unroll
        for (int ti = 0; ti < 4; ++ti)
            af[ti] = *(const bf16x8*)(As[cur] + (ti * 16 + m) * 40 + quad * 8);
#pragma unroll
        for (int tj = 0; tj < 2; ++tj)
            bfr[tj] = *(const bf16x8*)(Bs[cur] + (wave * 32 + tj * 16 + m) * 40 + quad * 8);
#pragma unroll
        for (int ti = 0; ti < 4; ++ti)
#pragma unroll
            for (int tj = 0; tj < 2; ++tj)
                acc[ti][tj] = __builtin_amdgcn_mfma_f32_16x16x32_bf16(
                    af[ti], bfr[tj], acc[ti][tj], 0, 0, 0);
        __syncthreads();
        cur ^= 1;
    }

    // epilogue: bias + relu, per-episode (32-row) column sums; 64 rows = 2 episodes
#pragma unroll
    for (int ep = 0; ep < 2; ++ep) {
#pragma unroll
        for (int tj = 0; tj < 2; ++tj) {
            int colL = wave * 32 + tj * 16 + m;
            float b = bfe[col0 + colL];
            float s1 = 0.f, s2 = 0.f;
#pragma unroll
            for (int p = 0; p < 2; ++p) {
                int ti = ep * 2 + p;
#pragma unroll
                for (int r = 0; r < 4; ++r) {
                    float v = fmaxf(acc[ti][tj][r] + b, 0.f);
                    s1 += v; s2 += v * v;
                }
            }
            s1 += __shfl_xor(s1, 16); s1 += __shfl_xor(s1, 32);
            s2 += __shfl_xor(s2, 16); s2 += __shfl_xor(s2, 32);
            if (lane < 16) sbuf[ep * 128 + colL] = make_float2(s1, s2);
        }
    }
    __syncthreads();
    {
        int ep = tid >> 7, cl = tid & 127;   // 256 threads = 2 eps x 128 cols
        float2 pr = sbuf[ep * 128 + cl];
        float mean = pr.x * (1.f / 32.f);
        float var  = (pr.y - 32.f * mean * mean) * (1.f / 31.f);   // ddof=1
        float sd   = sqrtf(fmaxf(var, 0.f));
        int e = blockIdx.x * 2 + ep;
        int f = col0 + cl;
        Z[(size_t)e * TDIM + 1 + f]   = mean;
        Z[(size_t)e * TDIM + 514 + f] = sd;
        Zb[(size_t)e * KP + 1 + f]    = f2bf(mean);
        Zb[(size_t)e * KP + 514 + f]  = f2bf(sd);
    }
}

// ---- Kernel 3a: bf16 MFMA LV GEMM, split-K=7, raw fp32 partials --------------
__global__ __launch_bounds__(256)
void k_lv_mfma(const unsigned short* __restrict__ Zb,
               const unsigned short* __restrict__ Wlt,
               float* __restrict__ Cacc)
{
    __shared__ unsigned short As[128 * 40];
    __shared__ unsigned short Bs[128 * 40];

    const int tid  = threadIdx.x;
    const int lane = tid & 63;
    const int wave = tid >> 6;
    const int wr = wave >> 1, wc = wave & 1;
    const int m = lane & 15, quad = lane >> 4;
    const int col0 = blockIdx.x * 128;
    const int row0 = blockIdx.y * 128;
    const int p    = blockIdx.z;
    const int it0  = (p < 5) ? p * 5 : 25 + (p - 5) * 4;
    const int itn  = (p < 5) ? 5 : 4;

    f32x4 acc[4][4];
#pragma unroll
    for (int i = 0; i < 4; ++i)
#pragma unroll
        for (int j = 0; j < 4; ++j) acc[i][j] = (f32x4){0.f, 0.f, 0.f, 0.f};

    const int srow = tid >> 2;
    const int skc  = tid & 3;

    for (int it = it0; it < it0 + itn; ++it) {
        int k0 = it * 32;
#pragma unroll
        for (int s = 0; s < 2; ++s) {
            int row = srow + s * 64;
            uint4 va = *(const uint4*)(Zb  + (size_t)(row0 + row) * KP + k0 + skc * 8);
            uint4 vb = *(const uint4*)(Wlt + (size_t)(col0 + row) * KP + k0 + skc * 8);
            *(uint4*)(As + row * 40 + skc * 8) = va;
            *(uint4*)(Bs + row * 40 + skc * 8) = vb;
        }
        __syncthreads();
        bf16x8 af[4], bfr[4];
#pragma unroll
        for (int t2 = 0; t2 < 4; ++t2) {
            af[t2]  = *(const bf16x8*)(As + (wr * 64 + t2 * 16 + m) * 40 + quad * 8);
            bfr[t2] = *(const bf16x8*)(Bs + (wc * 64 + t2 * 16 + m) * 40 + quad * 8);
        }
#pragma unroll
        for (int ti = 0; ti < 4; ++ti)
#pragma unroll
            for (int tj = 0; tj < 4; ++tj)
                acc[ti][tj] = __builtin_amdgcn_mfma_f32_16x16x32_bf16(
                    af[ti], bfr[tj], acc[ti][tj], 0, 0, 0);
        __syncthreads();
    }

    float* C = Cacc + (size_t)p * 512 * NP;
#pragma unroll
    for (int ti = 0; ti < 4; ++ti)
#pragma unroll
        for (int tj = 0; tj < 4; ++tj) {
            int c = col0 + wc * 64 + tj * 16 + m;
#pragma unroll
            for (int r = 0; r < 4; ++r) {
                int rg = row0 + wr * 64 + ti * 16 + quad * 4 + r;
                C[(size_t)rg * NP + c] = acc[ti][tj][r];
            }
        }
}

// ---- Kernel 3b: reduce partials + bias/clip/exp; build pairwise-GEMM operands
__global__ __launch_bounds__(256)
void k_lv_ep(const float* __restrict__ Cacc, const float* __restrict__ Zf,
             const float* __restrict__ blv,
             unsigned short* __restrict__ Xb, unsigned short* __restrict__ Yb,
             float* __restrict__ Hs_te, float* __restrict__ cterm)
{
    const int t = threadIdx.x;
    const int rl = t >> 3;
    const int ci = t & 7;
    const int r  = blockIdx.y * 32 + rl;
    const int c0 = blockIdx.x * 32 + ci * 4;
    const bool is_te = (r >= 256);

    float4 s = make_float4(0.f, 0.f, 0.f, 0.f);
#pragma unroll
    for (int p = 0; p < KSPLIT; ++p) {
        float4 v = *(const float4*)(Cacc + (size_t)p * 512 * NP + (size_t)r * NP + c0);
        s.x += v.x; s.y += v.y; s.z += v.z; s.w += v.w;
    }
    float sv[4] = {s.x, s.y, s.z, s.w};

    unsigned short* O = is_te ? (Yb + (size_t)(r - 256) * KK) : (Xb + (size_t)r * KK);
    float h = 0.f, ct = 0.f;
#pragma unroll
    for (int q = 0; q < 4; ++q) {
        int c = c0 + q;
        bool cok = (c < TDIM);
        ushort4 o = make_ushort4(0, 0, 0, 0);
        if (cok) {
            float x = fminf(fmaxf(sv[q] + blv[c], -9.f), -2.f);
            float E = expf(x);
            float R = expf(-x);
            float mm = Zf[(size_t)r * TDIM + c];
            if (!is_te) {
                o.x = f2bf(E + mm * mm);
                o.y = f2bf(R);
                o.z = f2bf(-2.f * mm * R);
                o.w = f2bf(-2.f * mm);
            } else {
                o.x = f2bf(R);
                o.y = f2bf(E + mm * mm);
                o.z = f2bf(mm);
                o.w = f2bf(mm * R);
                h  += x;
                ct += mm * mm * R;
            }
        }
        *(ushort4*)(O + 4 * c) = o;
    }
    if (is_te) {
        h  += __shfl_xor(h, 1);  h  += __shfl_xor(h, 2);  h  += __shfl_xor(h, 4);
        ct += __shfl_xor(ct, 1); ct += __shfl_xor(ct, 2); ct += __shfl_xor(ct, 4);
        if (ci == 0) {
            atomicAdd(Hs_te + (r - 256), h);
            atomicAdd(cterm + (r - 256), ct);
        }
    }
}

// ---- Kernel 4: pairwise GEMM S = X * Y^T, 256x256xKK bf16, split-K=16 --------
__global__ __launch_bounds__(256)
void k_pgemm(const unsigned short* __restrict__ Xb,
             const unsigned short* __restrict__ Yb,
             float* __restrict__ Sp)
{
    __shared__ unsigned short As[128 * 40];
    __shared__ unsigned short Bs[128 * 40];

    const int tid  = threadIdx.x;
    const int lane = tid & 63;
    const int wave = tid >> 6;
    const int wr = wave >> 1, wc = wave & 1;
    const int m = lane & 15, quad = lane >> 4;
    const int col0 = blockIdx.x * 128;
    const int row0 = blockIdx.y * 128;
    const int p    = blockIdx.z;           // 0..15; 132 iters = 4*9 + 12*8
    const int it0  = (p < 4) ? p * 9 : 36 + (p - 4) * 8;
    const int itn  = (p < 4) ? 9 : 8;

    f32x4 acc[4][4];
#pragma unroll
    for (int i = 0; i < 4; ++i)
#pragma unroll
        for (int j = 0; j < 4; ++j) acc[i][j] = (f32x4){0.f, 0.f, 0.f, 0.f};

    const int srow = tid >> 2;
    const int skc  = tid & 3;

    for (int it = it0; it < it0 + itn; ++it) {
        int k0 = it * 32;
#pragma unroll
        for (int s = 0; s < 2; ++s) {
            int row = srow + s * 64;
            uint4 va = *(const uint4*)(Xb + (size_t)(row0 + row) * KK + k0 + skc * 8);
            uint4 vb = *(const uint4*)(Yb + (size_t)(col0 + row) * KK + k0 + skc * 8);
            *(uint4*)(As + row * 40 + skc * 8) = va;
            *(uint4*)(Bs + row * 40 + skc * 8) = vb;
        }
        __syncthreads();
        bf16x8 af[4], bfr[4];
#pragma unroll
        for (int t2 = 0; t2 < 4; ++t2) {
            af[t2]  = *(const bf16x8*)(As + (wr * 64 + t2 * 16 + m) * 40 + quad * 8);
            bfr[t2] = *(const bf16x8*)(Bs + (wc * 64 + t2 * 16 + m) * 40 + quad * 8);
        }
#pragma unroll
        for (int ti = 0; ti < 4; ++ti)
#pragma unroll
            for (int tj = 0; tj < 4; ++tj)
                acc[ti][tj] = __builtin_amdgcn_mfma_f32_16x16x32_bf16(
                    af[ti], bfr[tj], acc[ti][tj], 0, 0, 0);
        __syncthreads();
    }

    float* C = Sp + (size_t)p * 65536;
#pragma unroll
    for (int ti = 0; ti < 4; ++ti)
#pragma unroll
        for (int tj = 0; tj < 4; ++tj) {
            int c = col0 + wc * 64 + tj * 16 + m;
#pragma unroll
            for (int r = 0; r < 4; ++r) {
                int rg = row0 + wr * 64 + ti * 16 + quad * 4 + r;
                C[(size_t)rg * 256 + c] = acc[ti][tj][r];
            }
        }
}

// ---- Kernel 5: row log_softmax + classes -------------------------------------
__global__ __launch_bounds__(256)
void k_soft(const float* __restrict__ Sp, const float* __restrict__ Hs_te,
            const float* __restrict__ cterm, float* __restrict__ outp)
{
    __shared__ float red[4], red2[4];
    const int i = blockIdx.x, j = threadIdx.x;
    float s = 0.f;
#pragma unroll
    for (int tc = 0; tc < 16; ++tc)
        s += Sp[((size_t)tc * 256 + i) * 256 + j];
    float v = -(0.5f * (s + cterm[j]) + Hs_te[j]);

    float m = v;
#pragma unroll
    for (int o = 32; o > 0; o >>= 1) m = fmaxf(m, __shfl_xor(m, o));
    if ((j & 63) == 0) red[j >> 6] = m;
    __syncthreads();
    m = fmaxf(fmaxf(red[0], red[1]), fmaxf(red[2], red[3]));

    float p = v - m;
    float t = expf(p);
#pragma unroll
    for (int o = 32; o > 0; o >>= 1) t += __shfl_xor(t, o);
    if ((j & 63) == 0) red2[j >> 6] = t;
    __syncthreads();
    t = red2[0] + red2[1] + red2[2] + red2[3];

    outp[(size_t)i * 256 + j] = p - logf(t);
    if (i == 0) outp[65536 + j] = (float)j;
}

// =================== Fallback fp32 path (ws too small) ========================
__global__ __launch_bounds__(256)
void k_fe_f32(const float* __restrict__ Atr, const float* __restrict__ Ate,
              const float* __restrict__ Wfe, const float* __restrict__ bfe,
              float* __restrict__ Z, float* __restrict__ muT_te)
{
    __shared__ float lds[4224];
    float* Ast = lds;
    float* Bs  = lds + 2112;
    const int tid = threadIdx.x;
    const int tx = tid & 15;
    const int ty = tid >> 4;
    const int col0 = blockIdx.x * 128;
    const int row0 = blockIdx.y * 128;
    const float* A = (row0 < 8192) ? Atr : Ate;
    const int ar0 = (row0 < 8192) ? row0 : (row0 - 8192);

    float acc[8][8];
#pragma unroll
    for (int i = 0; i < 8; ++i)
#pragma unroll
        for (int j = 0; j < 8; ++j) acc[i][j] = 0.f;

    for (int k0 = 0; k0 < 512; k0 += 16) {
#pragma unroll
        for (int s = 0; s < 2; ++s) {
            int u = tid + s * 256;
            int row = u >> 2, q = u & 3;
            float4 v = *(const float4*)(A + (size_t)(ar0 + row) * 512 + k0 + q * 4);
            Ast[(q * 4 + 0) * 132 + row] = v.x;
            Ast[(q * 4 + 1) * 132 + row] = v.y;
            Ast[(q * 4 + 2) * 132 + row] = v.z;
            Ast[(q * 4 + 3) * 132 + row] = v.w;
        }
#pragma unroll
        for (int s = 0; s < 2; ++s) {
            int u = tid + s * 256;
            int kk = u >> 5, c8 = u & 31;
            float4 v = *(const float4*)(Wfe + (size_t)(k0 + kk) * 512 + col0 + c8 * 4);
            *(float4*)(Bs + kk * 132 + c8 * 4) = v;
        }
        __syncthreads();
#pragma unroll
        for (int kk = 0; kk < 16; ++kk) {
            float4 a0 = *(const float4*)(Ast + kk * 132 + ty * 8);
            float4 a1 = *(const float4*)(Ast + kk * 132 + ty * 8 + 4);
            float4 b0 = *(const float4*)(Bs + kk * 132 + tx * 4);
            float4 b1 = *(const float4*)(Bs + kk * 132 + 64 + tx * 4);
            float av[8] = {a0.x, a0.y, a0.z, a0.w, a1.x, a1.y, a1.z, a1.w};
            float bv[8] = {b0.x, b0.y, b0.z, b0.w, b1.x, b1.y, b1.z, b1.w};
#pragma unroll
            for (int i = 0; i < 8; ++i)
#pragma unroll
                for (int j = 0; j < 8; ++j)
                    acc[i][j] = fmaf(av[i], bv[j], acc[i][j]);
        }
        __syncthreads();
    }

    float2* sbuf = (float2*)lds;
#pragma unroll
    for (int j = 0; j < 8; ++j) {
        int cl = (j < 4) ? (tx * 4 + j) : (64 + tx * 4 + (j - 4));
        float b = bfe[col0 + cl];
        float s1 = 0.f, s2 = 0.f;
#pragma unroll
        for (int i = 0; i < 8; ++i) {
            float v = acc[i][j] + b;
            v = fmaxf(v, 0.f);
            s1 += v; s2 += v * v;
        }
        sbuf[ty * 128 + cl] = make_float2(s1, s2);
    }
    __syncthreads();
    for (int idx = tid; idx < 512; idx += 256) {
        int ep = idx >> 7, cl = idx & 127;
        float S1 = 0.f, S2 = 0.f;
#pragma unroll
        for (int q = 0; q < 4; ++q) {
            float2 p = sbuf[(ep * 4 + q) * 128 + cl];
            S1 += p.x; S2 += p.y;
        }
        float mean = S1 * (1.f / 32.f);
        float var  = (S2 - 32.f * mean * mean) * (1.f / 31.f);
        float sd   = sqrtf(fmaxf(var, 0.f));
        int e = (row0 >> 5) + ep;
        int f = col0 + cl;
        Z[(size_t)e * TDIM + 1 + f]   = mean;
        Z[(size_t)e * TDIM + 514 + f] = sd;
        if (e >= 256) {
            int j2 = e - 256;
            muT_te[(size_t)(1 + f) * 256 + j2]   = mean;
            muT_te[(size_t)(514 + f) * 256 + j2] = sd;
        }
    }
}

__global__ __launch_bounds__(256)
void k_tgt_f32(const float* __restrict__ Ttr, const float* __restrict__ Tte,
               float* __restrict__ Z, float* __restrict__ muT_te,
               float* __restrict__ Hs_te)
{
    if (blockIdx.x == 0) Hs_te[threadIdx.x] = 0.f;
    int e = blockIdx.x * 256 + threadIdx.x;
    if (e >= 512) return;
    const float* p = (e < 256) ? (Ttr + (size_t)e * 32) : (Tte + (size_t)(e - 256) * 32);
    float S1 = 0.f, S2 = 0.f;
#pragma unroll
    for (int n = 0; n < 32; ++n) { float v = p[n]; S1 += v; S2 += v * v; }
    float mean = S1 * (1.f / 32.f);
    float var  = (S2 - 32.f * mean * mean) * (1.f / 31.f);
    float sd   = sqrtf(fmaxf(var, 0.f));
    Z[(size_t)e * TDIM + 0]   = mean;
    Z[(size_t)e * TDIM + 513] = sd;
    if (e >= 256) {
        muT_te[(size_t)0 * 256 + (e - 256)]   = mean;
        muT_te[(size_t)513 * 256 + (e - 256)] = sd;
    }
}

__global__ __launch_bounds__(256)
void k_lv(const float* __restrict__ Z, const float* __restrict__ Wlv,
          const float* __restrict__ blv,
          float* __restrict__ E_tr, float* __restrict__ R_tr,
          float* __restrict__ E_teT, float* __restrict__ R_teT,
          float* __restrict__ Hs_te)
{
    __shared__ float Ast[16 * 68];
    __shared__ float Bs[16 * 68];
    const int tid = threadIdx.x;
    const int tx = tid & 15;
    const int ty = tid >> 4;
    const int col0 = blockIdx.x * 64;
    const int row0 = blockIdx.y * 64;

    float acc[4][4];
#pragma unroll
    for (int i = 0; i < 4; ++i)
#pragma unroll
        for (int j = 0; j < 4; ++j) acc[i][j] = 0.f;

    for (int k0 = 0; k0 < TDIM; k0 += 16) {
        {
            int row = tid >> 2, kp = tid & 3;
            const float* src = Z + (size_t)(row0 + row) * TDIM + k0 + kp * 4;
            float x0 = 0.f, x1 = 0.f, x2 = 0.f, x3 = 0.f;
            if (k0 + kp * 4 + 1 < TDIM) { float2 v = *(const float2*)(src);     x0 = v.x; x1 = v.y; }
            if (k0 + kp * 4 + 3 < TDIM) { float2 v = *(const float2*)(src + 2); x2 = v.x; x3 = v.y; }
            Ast[(kp * 4 + 0) * 68 + row] = x0;
            Ast[(kp * 4 + 1) * 68 + row] = x1;
            Ast[(kp * 4 + 2) * 68 + row] = x2;
            Ast[(kp * 4 + 3) * 68 + row] = x3;
        }
        {
            int kk = tid >> 4, cg = tid & 15;
#pragma unroll
            for (int c = 0; c < 4; ++c) {
                int col = col0 + cg * 4 + c;
                float v = 0.f;
                if (k0 + kk < TDIM && col < TDIM)
                    v = Wlv[(size_t)(k0 + kk) * TDIM + col];
                Bs[kk * 68 + cg * 4 + c] = v;
            }
        }
        __syncthreads();
#pragma unroll
        for (int kk = 0; kk < 16; ++kk) {
            float4 a = *(const float4*)(Ast + kk * 68 + ty * 4);
            float4 b = *(const float4*)(Bs + kk * 68 + tx * 4);
            float av[4] = {a.x, a.y, a.z, a.w};
            float bv[4] = {b.x, b.y, b.z, b.w};
#pragma unroll
            for (int i = 0; i < 4; ++i)
#pragma unroll
                for (int j = 0; j < 4; ++j)
                    acc[i][j] = fmaf(av[i], bv[j], acc[i][j]);
        }
        __syncthreads();
    }

    float hpart[4] = {0.f, 0.f, 0.f, 0.f};
#pragma unroll
    for (int i = 0; i < 4; ++i) {
        int r = row0 + ty * 4 + i;
#pragma unroll
        for (int j = 0; j < 4; ++j) {
            int c = col0 + tx * 4 + j;
            if (c < TDIM) {
                float lv = acc[i][j] + blv[c];
                lv = fminf(fmaxf(lv, -9.f), -2.f);
                float E = expf(lv);
                float R = expf(-lv);
                if (r < 256) {
                    E_tr[(size_t)r * TDIM + c] = E;
                    R_tr[(size_t)r * TDIM + c] = R;
                } else {
                    E_teT[(size_t)c * 256 + (r - 256)] = E;
                    R_teT[(size_t)c * 256 + (r - 256)] = R;
                    hpart[i] += lv;
                }
            }
        }
    }
    if (row0 >= 256) {
        __syncthreads();
        float* hbuf = Ast;
#pragma unroll
        for (int i = 0; i < 4; ++i) hbuf[(ty * 4 + i) * 16 + tx] = hpart[i];
        __syncthreads();
        if (tid < 64) {
            float s = 0.f;
#pragma unroll
            for (int x = 0; x < 16; ++x) s += hbuf[tid * 16 + x];
            atomicAdd(Hs_te + (row0 - 256 + tid), s);
        }
    }
}

#define TCH 65
__global__ __launch_bounds__(256)
void k_pair(const float* __restrict__ Z, const float* __restrict__ E_tr,
            const float* __restrict__ R_tr, const float* __restrict__ muT_te,
            const float* __restrict__ E_teT, const float* __restrict__ R_teT,
            float* __restrict__ Sp)
{
    __shared__ float Lm[8 * 68], Le[8 * 68], Lr[8 * 68];
    const int tid = threadIdx.x;
    const int i0 = blockIdx.x * 8;
    const int t0 = blockIdx.y * TCH;
    const int tlen = min(TCH, TDIM - t0);

    if (tid < tlen) {
#pragma unroll
        for (int r = 0; r < 8; ++r) {
            size_t off = (size_t)(i0 + r) * TDIM + t0 + tid;
            Lm[r * 68 + tid] = Z[off];
            Le[r * 68 + tid] = E_tr[off];
            Lr[r * 68 + tid] = R_tr[off];
        }
    }
    __syncthreads();

    float S[8];
#pragma unroll
    for (int r = 0; r < 8; ++r) S[r] = 0.f;
    const int j = tid;
    for (int tt = 0; tt < tlen; ++tt) {
        size_t o = (size_t)(t0 + tt) * 256 + j;
        float m2 = muT_te[o], e2 = E_teT[o], r2 = R_teT[o];
#pragma unroll
        for (int r = 0; r < 8; ++r) {
            float m1 = Lm[r * 68 + tt];
            float e1 = Le[r * 68 + tt];
            float r1 = Lr[r * 68 + tt];
            float d = m1 - m2;
            S[r] += e1 * r2 + e2 * r1 + d * d * (r1 + r2);
        }
    }
#pragma unroll
    for (int r = 0; r < 8; ++r)
        Sp[((size_t)blockIdx.y * 256 + i0 + r) * 256 + j] = S[r];
}

__global__ __launch_bounds__(256)
void k_soft_fb(const float* __restrict__ Sp, const float* __restrict__ Hs_te,
               float* __restrict__ outp)
{
    __shared__ float red[4], red2[4];
    const int i = blockIdx.x, j = threadIdx.x;
    float s = 0.f;
#pragma unroll
    for (int tc = 0; tc < 16; ++tc)
        s += Sp[((size_t)tc * 256 + i) * 256 + j];
    float v = -(0.5f * s + Hs_te[j]);

    float m = v;
#pragma unroll
    for (int o = 32; o > 0; o >>= 1) m = fmaxf(m, __shfl_xor(m, o));
    if ((j & 63) == 0) red[j >> 6] = m;
    __syncthreads();
    m = fmaxf(fmaxf(red[0], red[1]), fmaxf(red[2], red[3]));

    float p = v - m;
    float t = expf(p);
#pragma unroll
    for (int o = 32; o > 0; o >>= 1) t += __shfl_xor(t, o);
    if ((j & 63) == 0) red2[j >> 6] = t;
    __syncthreads();
    t = red2[0] + red2[1] + red2[2] + red2[3];

    outp[(size_t)i * 256 + j] = p - logf(t);
    if (i == 0) outp[65536 + j] = (float)j;
}

extern "C" void kernel_launch(void* const* d_in, const int* in_sizes, int n_in,
                              void* d_out, int out_size, void* d_ws, size_t ws_size,
                              hipStream_t stream)
{
    const float* tri = (const float*)d_in[0];
    const float* trt = (const float*)d_in[1];
    const float* tei = (const float*)d_in[2];
    const float* tet = (const float*)d_in[3];
    const float* Wfe = (const float*)d_in[4];
    const float* bfe = (const float*)d_in[5];
    const float* Wlv = (const float*)d_in[6];
    const float* blv = (const float*)d_in[7];
    float* outp = (float*)d_out;

    // ---- fast-path layout ----
    char* base = (char*)d_ws;
    float* Z     = (float*)base;                                   // 512*1026*4 = 2,101,248
    float* Sp    = (float*)(base + 2101248);                       // 16*256*256*4 = 4,194,304
    float* Hs_te = (float*)(base + 2101248 + 4194304);             // 1024
    float* cterm = (float*)(base + 2101248 + 4194304 + 1024);      // 1024
    float* Cacc  = (float*)(base + 6296576 + 1024);                // 7*512*1152*4 = 16,515,072
    unsigned short* Wt = (unsigned short*)(base + 6297600 + 16515072);   // 524,288
    unsigned short* Xb = (unsigned short*)(base + 22812672 + 524288);    // 256*4224*2 = 2,162,688
    unsigned short* Yb = (unsigned short*)(base + 23336960 + 2162688);   // 2,162,688
    // Wlt/Zb alias the Sp region (consumed by k_lv_mfma before k_pgemm writes Sp)
    unsigned short* Wlt = (unsigned short*)Sp;                           // NP*KP*2 = 2,433,024
    unsigned short* Zb  = (unsigned short*)((char*)Sp + 2433024);        // 512*KP*2 = 1,081,344

    const size_t need = 23336960ull + 2162688ull + 2162688ull;           // 27,662,336 B
    const bool fast = (ws_size >= need);

    if (fast) {
        k_cvtboth<<<dim3(36, 33, 3), 256, 0, stream>>>(Wfe, Wlv, Wt, Wlt,
                                                       trt, tet, Z, Zb, Hs_te, cterm);
        k_fe_mfma<<<dim3(256, 4), 256, 0, stream>>>(tri, tei, Wt, bfe, Z, Zb);
        k_lv_mfma<<<dim3(9, 4, KSPLIT), 256, 0, stream>>>(Zb, Wlt, Cacc);
        k_lv_ep  <<<dim3(33, 16), 256, 0, stream>>>(Cacc, Z, blv, Xb, Yb, Hs_te, cterm);
        k_pgemm  <<<dim3(2, 2, 16), 256, 0, stream>>>(Xb, Yb, Sp);
        k_soft   <<<256, 256, 0, stream>>>(Sp, Hs_te, cterm, outp);
    } else {
        // fallback fp32 path, old layout
        float* Zf    = (float*)d_ws;
        float* E_tr  = Zf + (size_t)512 * TDIM;
        float* R_tr  = E_tr + (size_t)256 * TDIM;
        float* muT   = R_tr + (size_t)256 * TDIM;
        float* E_teT = muT + (size_t)TDIM * 256;
        float* R_teT = E_teT + (size_t)TDIM * 256;
        float* Hs    = R_teT + (size_t)TDIM * 256;
        float* Spf   = Hs + 256;
        k_fe_f32 <<<dim3(4, 128), 256, 0, stream>>>(tri, tei, Wfe, bfe, Zf, muT);
        k_tgt_f32<<<2, 256, 0, stream>>>(trt, tet, Zf, muT, Hs);
        k_lv     <<<dim3(17, 8), 256, 0, stream>>>(Zf, Wlv, blv, E_tr, R_tr, E_teT, R_teT, Hs);
        k_pair   <<<dim3(32, 16), 256, 0, stream>>>(Zf, E_tr, R_tr, muT, E_teT, R_teT, Spf);
        k_soft_fb<<<256, 256, 0, stream>>>(Spf, Hs, outp);
    }
}